// Round 1
// 453.664 us; speedup vs baseline: 1.1494x; 1.1494x over previous
//
#include <hip/hip_runtime.h>
#include <hip/hip_bf16.h>

#define NN    20000
#define BB    2
#define EE    320000
#define MROWS (NN * BB)   // 40000

typedef __bf16 bf16x8 __attribute__((ext_vector_type(8)));
typedef float  floatx4 __attribute__((ext_vector_type(4)));

// Channel permutation of the 1024 fused output channels (c = head*32+chan):
//   j in [0,512):    c = j>>1;        j even -> k[c], j odd -> v[c]
//   j in [512,1024): c = (j-512)>>1;  j even -> q[c], j odd -> r[c]
// So a uint32 at row*512 + c       = (k[c] | v[c]<<16)  (bf16 pair)
//    a uint32 at row*512 + 256 + c = (q[c] | r[c]<<16)

// ---------------------------------------------------------------------------
// Weight transpose + permute: wt[1024][256] bf16, wt[j][k] = W_sel[k][col(j)].
// LDS-tiled so both global reads and writes are coalesced.
// ---------------------------------------------------------------------------
__global__ __launch_bounds__(256) void transpose_weights(
    const float* __restrict__ Wq, const float* __restrict__ Wk,
    const float* __restrict__ Wv, const float* __restrict__ Wr,
    __hip_bfloat16* __restrict__ wt) {
  __shared__ float TA[32][65];
  __shared__ float TB[32][65];
  int bt = blockIdx.x;                 // 0..15
  const float *A, *B;
  int c0, jbase;
  if (bt < 8) { A = Wk; B = Wv; c0 = 32 * bt;      jbase = 64 * bt; }
  else        { A = Wq; B = Wr; c0 = 32 * (bt-8);  jbase = 512 + 64 * (bt-8); }
  int t = threadIdx.x;
  int krow = t >> 2;                   // 0..63
  int cc = (t & 3) * 8;                // 0,8,16,24
  int sel = t >> 7;                    // write phase: 0->A, 1->B
  int u = t & 127;
  int ci = u >> 2;                     // 0..31
  int kk0 = (u & 3) * 16;              // 0,16,32,48

  for (int kt = 0; kt < 4; ++kt) {
    int k = kt * 64 + krow;
    float4 a0 = *(const float4*)(A + (size_t)k * 256 + c0 + cc);
    float4 a1 = *(const float4*)(A + (size_t)k * 256 + c0 + cc + 4);
    float4 b0 = *(const float4*)(B + (size_t)k * 256 + c0 + cc);
    float4 b1 = *(const float4*)(B + (size_t)k * 256 + c0 + cc + 4);
    __syncthreads();                   // previous write phase done
    TA[cc+0][krow]=a0.x; TA[cc+1][krow]=a0.y; TA[cc+2][krow]=a0.z; TA[cc+3][krow]=a0.w;
    TA[cc+4][krow]=a1.x; TA[cc+5][krow]=a1.y; TA[cc+6][krow]=a1.z; TA[cc+7][krow]=a1.w;
    TB[cc+0][krow]=b0.x; TB[cc+1][krow]=b0.y; TB[cc+2][krow]=b0.z; TB[cc+3][krow]=b0.w;
    TB[cc+4][krow]=b1.x; TB[cc+5][krow]=b1.y; TB[cc+6][krow]=b1.z; TB[cc+7][krow]=b1.w;
    __syncthreads();
    float (*T)[65] = sel ? TB : TA;
    int j = jbase + 2 * ci + sel;
    __hip_bfloat16* dst = wt + (size_t)j * 256 + kt * 64 + kk0;
    #pragma unroll
    for (int q = 0; q < 16; ++q) dst[q] = __float2bfloat16(T[ci][kk0 + q]);
  }
}

__global__ void prep_bias(const float* __restrict__ bq, const float* __restrict__ bk,
                          const float* __restrict__ bv, const float* __restrict__ br,
                          float* __restrict__ bcat) {
  int j = blockIdx.x * 256 + threadIdx.x;   // grid 4 x 256
  float val;
  if (j < 512) { int c = j >> 1;         val = (j & 1) ? bv[c] : bk[c]; }
  else         { int c = (j - 512) >> 1; val = (j & 1) ? br[c] : bq[c]; }
  bcat[j] = val;
}

// wesum[h][d] = sum_c We[d][h*32+c]
__global__ void prep_wesum(const float* __restrict__ We, float* __restrict__ wesum) {
  int i = threadIdx.x;           // 0..511
  int h = i >> 6, d = i & 63;
  float s = 0.f;
  for (int c = 0; c < 32; ++c) s += We[(size_t)d * 256 + h * 32 + c];
  wesum[h * 64 + d] = s;
}

__global__ void zero_ints(int* __restrict__ p, int n) {
  int i = blockIdx.x * 256 + threadIdx.x;
  if (i < n) p[i] = 0;
}

// ---------------------------------------------------------------------------
// Fused q|k|v|r GEMM, channel-permuted bf16 output.
// Tile M=64 x N=256 (x re-read only 4x), BK=32, 4 waves each 64x64 (4x4 frags).
// LDS row stride 40 elems (80 B): 16B-aligned frag reads, ~2-way banks (free).
// ---------------------------------------------------------------------------
__global__ __launch_bounds__(256) void gemm_qkvr(
    const float* __restrict__ x,     // [MROWS][256] fp32
    const __bf16* __restrict__ wt,   // [1024][256] bf16 (n-major, permuted)
    const float* __restrict__ bcat,  // [1024] permuted
    __hip_bfloat16* __restrict__ out) {  // [MROWS][1024] bf16 permuted
  const int LSTR = 40;
  __shared__ __attribute__((aligned(16))) __bf16 As[64 * LSTR];
  __shared__ __attribute__((aligned(16))) __bf16 Bs[256 * LSTR];

  int m0 = blockIdx.y * 64;
  int n0 = blockIdx.x * 256;
  int t = threadIdx.x;
  int w = t >> 6, l = t & 63;
  int lr = l & 15, lq = l >> 4;
  int ar = t >> 2, ac = (t & 3) * 8;   // A staging: row, col

  floatx4 acc[4][4] = {};              // [mt][nt]

  for (int ks = 0; ks < 8; ++ks) {
    const float* xp = x + (size_t)(m0 + ar) * 256 + ks * 32 + ac;
    float4 f0 = *(const float4*)xp;
    float4 f1 = *(const float4*)(xp + 4);
    bf16x8 av;
    av[0] = (__bf16)f0.x; av[1] = (__bf16)f0.y;
    av[2] = (__bf16)f0.z; av[3] = (__bf16)f0.w;
    av[4] = (__bf16)f1.x; av[5] = (__bf16)f1.y;
    av[6] = (__bf16)f1.z; av[7] = (__bf16)f1.w;
    const __bf16* wp = wt + (size_t)(n0 + t) * 256 + ks * 32;
    bf16x8 b0 = *(const bf16x8*)(wp);
    bf16x8 b1 = *(const bf16x8*)(wp + 8);
    bf16x8 b2 = *(const bf16x8*)(wp + 16);
    bf16x8 b3 = *(const bf16x8*)(wp + 24);
    __syncthreads();                   // previous step's frag reads done
    *(bf16x8*)&As[ar * LSTR + ac] = av;
    __bf16* bsr = &Bs[t * LSTR];
    *(bf16x8*)(bsr)      = b0;
    *(bf16x8*)(bsr + 8)  = b1;
    *(bf16x8*)(bsr + 16) = b2;
    *(bf16x8*)(bsr + 24) = b3;
    __syncthreads();
    bf16x8 af[4], bf_[4];
    #pragma unroll
    for (int mt = 0; mt < 4; ++mt)
      af[mt] = *(const bf16x8*)&As[(16 * mt + lr) * LSTR + lq * 8];
    #pragma unroll
    for (int nt = 0; nt < 4; ++nt)
      bf_[nt] = *(const bf16x8*)&Bs[(64 * w + 16 * nt + lr) * LSTR + lq * 8];
    #pragma unroll
    for (int mt = 0; mt < 4; ++mt)
      #pragma unroll
      for (int nt = 0; nt < 4; ++nt)
        acc[mt][nt] = __builtin_amdgcn_mfma_f32_16x16x32_bf16(af[mt], bf_[nt], acc[mt][nt], 0, 0, 0);
  }

  // C/D: col = lane&15, row = (lane>>4)*4 + reg
  #pragma unroll
  for (int mt = 0; mt < 4; ++mt)
    #pragma unroll
    for (int nt = 0; nt < 4; ++nt)
      #pragma unroll
      for (int r = 0; r < 4; ++r) {
        int gr = m0 + 16 * mt + lq * 4 + r;
        int gc = n0 + 64 * w + 16 * nt + lr;
        out[(size_t)gr * 1024 + gc] = __float2bfloat16(acc[mt][nt][r] + bcat[gc]);
      }
}

// ---------------------------------------------------------------------------
// esum[e][h] = edata[e] . wesum[h] — one thread per edge, wesum in LDS.
// ---------------------------------------------------------------------------
__global__ __launch_bounds__(256) void esum2_kernel(
    const float* __restrict__ edata,
    const float* __restrict__ wesum,
    float* __restrict__ esum) {
  __shared__ float wl[512];
  int t = threadIdx.x;
  wl[t] = wesum[t];
  wl[t + 256] = wesum[t + 256];
  __syncthreads();
  int e = blockIdx.x * 256 + t;
  if (e >= EE) return;
  float acc[8] = {};
  const float* row = edata + (size_t)e * 64;
  for (int d = 0; d < 64; d += 4) {
    float4 v = *(const float4*)(row + d);
    #pragma unroll
    for (int h = 0; h < 8; ++h) {
      const float* wv = &wl[h * 64 + d];
      acc[h] += v.x * wv[0] + v.y * wv[1] + v.z * wv[2] + v.w * wv[3];
    }
  }
  #pragma unroll
  for (int h = 0; h < 8; ++h) esum[(size_t)e * 8 + h] = acc[h];
}

// ---------------------------------------------------------------------------
// CSR build: histogram, scan (1 block), scatter
// ---------------------------------------------------------------------------
__global__ void hist_kernel(const int* __restrict__ dst, int* __restrict__ counts) {
  int e = blockIdx.x * 256 + threadIdx.x;
  if (e < EE) atomicAdd(&counts[dst[e]], 1);
}

__global__ void scan_kernel(const int* __restrict__ counts,
                            int* __restrict__ offsets,
                            int* __restrict__ cursor) {
  __shared__ int part[256];
  int t = threadIdx.x;
  const int per = (NN + 255) / 256;   // 79
  int lo = t * per, hi = min(lo + per, NN);
  int s = 0;
  for (int i = lo; i < hi; ++i) s += counts[i];
  part[t] = s;
  __syncthreads();
  for (int off = 1; off < 256; off <<= 1) {
    int v = (t >= off) ? part[t - off] : 0;
    __syncthreads();
    part[t] += v;
    __syncthreads();
  }
  int base = (t == 0) ? 0 : part[t - 1];
  for (int i = lo; i < hi; ++i) {
    offsets[i] = base;
    cursor[i] = base;
    base += counts[i];
  }
  if (t == 255) offsets[NN] = base;
}

__global__ void scatter_kernel(const int* __restrict__ dst,
                               int* __restrict__ cursor,
                               int* __restrict__ sorted) {
  int e = blockIdx.x * 256 + threadIdx.x;
  if (e < EE) {
    int p = atomicAdd(&cursor[dst[e]], 1);
    sorted[p] = e;
  }
}

// ---------------------------------------------------------------------------
// Fused logits + softmax + V-aggregation + residual, fp32 out.
// ONE WAVE per (dst,b); lane l owns channels 4l..4l+3 (head h = l>>3).
//  - kv row read as one dwordx4 per lane (same coalescing as before, 1/4 the
//    address/unpack/softmax instruction replication of the 4-wave version).
//  - dot-reduce: 3 shfl_xor over the 8 lanes of a head (was 5 over 32 lanes).
//  - NO online-max: logits are bounded (|lg| << 88), so p = exp(lg) directly.
//    Removes max/rescale chain AND makes every edge's exp independent (the
//    only loop-carried deps are the z/acc FMA accumulators).
//  - depth-2 prefetch; (src,edge) indices broadcast via v_readlane (scalar
//    addressing, no LDS, no block barriers — waves have divergent trip counts).
// ---------------------------------------------------------------------------
__global__ __launch_bounds__(256) void aggregate_kernel(
    const unsigned int* __restrict__ qkvr,  // [MROWS][512] uints (kv | qr pairs)
    const float* __restrict__ esum,         // [E][8]
    const int* __restrict__ offsets,
    const int* __restrict__ sorted,
    const int* __restrict__ src,
    float* __restrict__ out) {              // [MROWS][256] fp32
  int t = threadIdx.x;
  int w = t >> 6, l = t & 63;
  int nb = blockIdx.x * 4 + w;              // grid 10000 -> 40000 waves
  int b = nb & 1, n = nb >> 1;
  int h = l >> 3;                           // head of channels 4l..4l+3
  int beg = offsets[n], end = offsets[n + 1];

  uint4 qr4 = *(const uint4*)(qkvr + (size_t)nb * 512 + 256 + l * 4);
  float q0 = __uint_as_float(qr4.x << 16);
  float q1 = __uint_as_float(qr4.y << 16);
  float q2 = __uint_as_float(qr4.z << 16);
  float q3 = __uint_as_float(qr4.w << 16);

  const unsigned* kvbase = qkvr + (size_t)b * 512 + l * 4;  // + s*1024 per edge
  const float* esbase = esum + h;                            // + e*8 per edge

  float z = 0.f, a0 = 0.f, a1 = 0.f, a2 = 0.f, a3 = 0.f;

  for (int base = beg; base < end; base += 64) {
    int chunk = min(64, end - base);
    int e_l = 0, s_l = 0;
    if (l < chunk) { e_l = sorted[base + l]; s_l = src[e_l]; }
    uint4 kvA = {0, 0, 0, 0}, kvB = {0, 0, 0, 0};
    float esA = 0.f, esB = 0.f;
    {
      int s0 = __builtin_amdgcn_readlane(s_l, 0);
      int e0 = __builtin_amdgcn_readlane(e_l, 0);
      kvA = *(const uint4*)(kvbase + (size_t)s0 * 1024);
      esA = esbase[(size_t)e0 * 8];
      if (chunk > 1) {
        int s1 = __builtin_amdgcn_readlane(s_l, 1);
        int e1 = __builtin_amdgcn_readlane(e_l, 1);
        kvB = *(const uint4*)(kvbase + (size_t)s1 * 1024);
        esB = esbase[(size_t)e1 * 8];
      }
    }
    for (int i = 0; i < chunk; ++i) {
      uint4 kv = kvA; float es = esA;
      kvA = kvB; esA = esB;
      if (i + 2 < chunk) {
        int s2 = __builtin_amdgcn_readlane(s_l, i + 2);
        int e2 = __builtin_amdgcn_readlane(e_l, i + 2);
        kvB = *(const uint4*)(kvbase + (size_t)s2 * 1024);
        esB = esbase[(size_t)e2 * 8];
      }
      float k0 = __uint_as_float(kv.x << 16);
      float k1 = __uint_as_float(kv.y << 16);
      float k2 = __uint_as_float(kv.z << 16);
      float k3 = __uint_as_float(kv.w << 16);
      float part = k0 * q0 + k1 * q1 + k2 * q2 + k3 * q3;
      part += __shfl_xor(part, 1, 64);
      part += __shfl_xor(part, 2, 64);
      part += __shfl_xor(part, 4, 64);
      float p = __expf(part * 0.17677669529663687f + es);
      z += p;
      float v0 = __uint_as_float(kv.x & 0xFFFF0000u);
      float v1 = __uint_as_float(kv.y & 0xFFFF0000u);
      float v2 = __uint_as_float(kv.z & 0xFFFF0000u);
      float v3 = __uint_as_float(kv.w & 0xFFFF0000u);
      a0 += p * v0; a1 += p * v1; a2 += p * v2; a3 += p * v3;
    }
  }
  float inv = (z > 0.f) ? (1.0f / z) : 0.f;
  float r0 = __uint_as_float(qr4.x & 0xFFFF0000u);
  float r1 = __uint_as_float(qr4.y & 0xFFFF0000u);
  float r2 = __uint_as_float(qr4.z & 0xFFFF0000u);
  float r3 = __uint_as_float(qr4.w & 0xFFFF0000u);
  float4 o = make_float4(a0 * inv + r0, a1 * inv + r1,
                         a2 * inv + r2, a3 * inv + r3);
  *(float4*)(out + (size_t)nb * 256 + l * 4) = o;
}

// ---------------------------------------------------------------------------
extern "C" void kernel_launch(void* const* d_in, const int* in_sizes, int n_in,
                              void* d_out, int out_size, void* d_ws, size_t ws_size,
                              hipStream_t stream) {
  (void)in_sizes; (void)n_in; (void)out_size; (void)ws_size;
  const float* x     = (const float*)d_in[0];
  const float* edata = (const float*)d_in[1];
  const int* esrc    = (const int*)d_in[2];
  const int* edst    = (const int*)d_in[3];
  const float* Wq    = (const float*)d_in[4];
  const float* bq    = (const float*)d_in[5];
  const float* Wk    = (const float*)d_in[6];
  const float* bk    = (const float*)d_in[7];
  const float* Wv    = (const float*)d_in[8];
  const float* bv    = (const float*)d_in[9];
  const float* We    = (const float*)d_in[10];
  const float* Wr    = (const float*)d_in[11];
  const float* br    = (const float*)d_in[12];
  float* out = (float*)d_out;     // fp32 output

  char* ws = (char*)d_ws;
  size_t off = 0;
  auto carve = [&](size_t bytes) -> void* {
    void* p = ws + off;
    off += (bytes + 255) & ~(size_t)255;
    return p;
  };
  int* counts    = (int*)carve((size_t)NN * 4);
  int* offsets   = (int*)carve((size_t)(NN + 1) * 4);
  int* cursor    = (int*)carve((size_t)NN * 4);
  int* sorted    = (int*)carve((size_t)EE * 4);               // 1.28 MB
  __hip_bfloat16* wt = (__hip_bfloat16*)carve((size_t)1024 * 256 * 2);
  float* bcat    = (float*)carve(1024 * 4);
  float* wesum   = (float*)carve(8 * 64 * 4);
  float* esum    = (float*)carve((size_t)EE * 8 * 4);         // 10.24 MB
  __hip_bfloat16* qkvr = (__hip_bfloat16*)carve((size_t)MROWS * 1024 * 2); // 81.9 MB

  zero_ints<<<(NN + 255) / 256, 256, 0, stream>>>(counts, NN);
  transpose_weights<<<16, 256, 0, stream>>>(Wq, Wk, Wv, Wr, wt);
  prep_bias<<<4, 256, 0, stream>>>(bq, bk, bv, br, bcat);
  prep_wesum<<<1, 512, 0, stream>>>(We, wesum);
  hist_kernel<<<(EE + 255) / 256, 256, 0, stream>>>(edst, counts);
  scan_kernel<<<1, 256, 0, stream>>>(counts, offsets, cursor);
  scatter_kernel<<<(EE + 255) / 256, 256, 0, stream>>>(edst, cursor, sorted);
  gemm_qkvr<<<dim3(4, 625), 256, 0, stream>>>(x, (const __bf16*)wt, bcat, qkvr);
  esum2_kernel<<<(EE + 255) / 256, 256, 0, stream>>>(edata, wesum, esum);
  aggregate_kernel<<<MROWS / 4, 256, 0, stream>>>((const unsigned int*)qkvr, esum,
                                                  offsets, sorted, esrc, out);
}

// Round 2
// 448.530 us; speedup vs baseline: 1.1626x; 1.0114x over previous
//
#include <hip/hip_runtime.h>
#include <hip/hip_bf16.h>

#define NN    20000
#define BB    2
#define EE    320000
#define MROWS (NN * BB)   // 40000

typedef __bf16 bf16x8 __attribute__((ext_vector_type(8)));
typedef float  floatx4 __attribute__((ext_vector_type(4)));

// Channel permutation of the 1024 fused output channels (c = head*32+chan):
//   j in [0,512):    c = j>>1;        j even -> k[c], j odd -> v[c]
//   j in [512,1024): c = (j-512)>>1;  j even -> q[c], j odd -> r[c]
// So a uint32 at row*512 + c       = (k[c] | v[c]<<16)  (bf16 pair)
//    a uint32 at row*512 + 256 + c = (q[c] | r[c]<<16)

// ---------------------------------------------------------------------------
// Weight transpose + permute: wt[1024][256] bf16, wt[j][k] = W_sel[k][col(j)].
// ---------------------------------------------------------------------------
__global__ __launch_bounds__(256) void transpose_weights(
    const float* __restrict__ Wq, const float* __restrict__ Wk,
    const float* __restrict__ Wv, const float* __restrict__ Wr,
    __hip_bfloat16* __restrict__ wt) {
  __shared__ float TA[32][65];
  __shared__ float TB[32][65];
  int bt = blockIdx.x;                 // 0..15
  const float *A, *B;
  int c0, jbase;
  if (bt < 8) { A = Wk; B = Wv; c0 = 32 * bt;      jbase = 64 * bt; }
  else        { A = Wq; B = Wr; c0 = 32 * (bt-8);  jbase = 512 + 64 * (bt-8); }
  int t = threadIdx.x;
  int krow = t >> 2;                   // 0..63
  int cc = (t & 3) * 8;                // 0,8,16,24
  int sel = t >> 7;                    // write phase: 0->A, 1->B
  int u = t & 127;
  int ci = u >> 2;                     // 0..31
  int kk0 = (u & 3) * 16;              // 0,16,32,48

  for (int kt = 0; kt < 4; ++kt) {
    int k = kt * 64 + krow;
    float4 a0 = *(const float4*)(A + (size_t)k * 256 + c0 + cc);
    float4 a1 = *(const float4*)(A + (size_t)k * 256 + c0 + cc + 4);
    float4 b0 = *(const float4*)(B + (size_t)k * 256 + c0 + cc);
    float4 b1 = *(const float4*)(B + (size_t)k * 256 + c0 + cc + 4);
    __syncthreads();                   // previous write phase done
    TA[cc+0][krow]=a0.x; TA[cc+1][krow]=a0.y; TA[cc+2][krow]=a0.z; TA[cc+3][krow]=a0.w;
    TA[cc+4][krow]=a1.x; TA[cc+5][krow]=a1.y; TA[cc+6][krow]=a1.z; TA[cc+7][krow]=a1.w;
    TB[cc+0][krow]=b0.x; TB[cc+1][krow]=b0.y; TB[cc+2][krow]=b0.z; TB[cc+3][krow]=b0.w;
    TB[cc+4][krow]=b1.x; TB[cc+5][krow]=b1.y; TB[cc+6][krow]=b1.z; TB[cc+7][krow]=b1.w;
    __syncthreads();
    float (*T)[65] = sel ? TB : TA;
    int j = jbase + 2 * ci + sel;
    __hip_bfloat16* dst = wt + (size_t)j * 256 + kt * 64 + kk0;
    #pragma unroll
    for (int q = 0; q < 16; ++q) dst[q] = __float2bfloat16(T[ci][kk0 + q]);
  }
}

__global__ void prep_bias(const float* __restrict__ bq, const float* __restrict__ bk,
                          const float* __restrict__ bv, const float* __restrict__ br,
                          float* __restrict__ bcat) {
  int j = blockIdx.x * 256 + threadIdx.x;   // grid 4 x 256
  float val;
  if (j < 512) { int c = j >> 1;         val = (j & 1) ? bv[c] : bk[c]; }
  else         { int c = (j - 512) >> 1; val = (j & 1) ? br[c] : bq[c]; }
  bcat[j] = val;
}

// wesum[h][d] = sum_c We[d][h*32+c]
__global__ void prep_wesum(const float* __restrict__ We, float* __restrict__ wesum) {
  int i = threadIdx.x;           // 0..511
  int h = i >> 6, d = i & 63;
  float s = 0.f;
  for (int c = 0; c < 32; ++c) s += We[(size_t)d * 256 + h * 32 + c];
  wesum[h * 64 + d] = s;
}

__global__ void zero_ints(int* __restrict__ p, int n) {
  int i = blockIdx.x * 256 + threadIdx.x;
  if (i < n) p[i] = 0;
}

// ---------------------------------------------------------------------------
// CSR build: histogram, scan (1 block), scatter
// ---------------------------------------------------------------------------
__global__ void hist_kernel(const int* __restrict__ dst, int* __restrict__ counts) {
  int e = blockIdx.x * 256 + threadIdx.x;
  if (e < EE) atomicAdd(&counts[dst[e]], 1);
}

__global__ void scan_kernel(const int* __restrict__ counts,
                            int* __restrict__ offsets,
                            int* __restrict__ cursor) {
  __shared__ int part[256];
  int t = threadIdx.x;
  const int per = (NN + 255) / 256;   // 79
  int lo = t * per, hi = min(lo + per, NN);
  int s = 0;
  for (int i = lo; i < hi; ++i) s += counts[i];
  part[t] = s;
  __syncthreads();
  for (int off = 1; off < 256; off <<= 1) {
    int v = (t >= off) ? part[t - off] : 0;
    __syncthreads();
    part[t] += v;
    __syncthreads();
  }
  int base = (t == 0) ? 0 : part[t - 1];
  for (int i = lo; i < hi; ++i) {
    offsets[i] = base;
    cursor[i] = base;
    base += counts[i];
  }
  if (t == 255) offsets[NN] = base;
}

// Writes src in CSR order (ssrc, coalesced read in aggregate) and the
// sorted position of each edge (pos) so esum can be produced pre-sorted.
__global__ void scatter_kernel(const int* __restrict__ dst,
                               const int* __restrict__ src,
                               int* __restrict__ cursor,
                               int* __restrict__ ssrc,
                               int* __restrict__ pos) {
  int e = blockIdx.x * 256 + threadIdx.x;
  if (e < EE) {
    int p = atomicAdd(&cursor[dst[e]], 1);
    ssrc[p] = src[e];
    pos[e] = p;
  }
}

// ---------------------------------------------------------------------------
// Fused dispatch: qkvr GEMM blocks (2500) interleaved 2:1 with esum blocks
// (1250) so the mem-bound edge-feature pass overlaps the MFMA-bound GEMM.
// GEMM: tile M=64 x N=256, BK=32, 4 waves each 64x64 (4x4 frags), LDS row
// stride 40 elems (16B-aligned frag reads, ~2-way banks = free).
// esum: esum[pos[e]][h] = edata[e] . wesum[h]  (written in CSR order).
// ---------------------------------------------------------------------------
__global__ __launch_bounds__(256) void fused_gemm_esum(
    const float* __restrict__ x,     // [MROWS][256] fp32
    const __bf16* __restrict__ wt,   // [1024][256] bf16 (n-major, permuted)
    const float* __restrict__ bcat,  // [1024] permuted
    __hip_bfloat16* __restrict__ outq,  // [MROWS][1024] bf16 permuted
    const float* __restrict__ edata,
    const float* __restrict__ wesum,
    const int* __restrict__ pos,
    float* __restrict__ esum) {      // [E][8] in CSR order
  const int LSTR = 40;
  __shared__ __attribute__((aligned(16))) __bf16 ABs[(64 + 256) * LSTR];
  int bid = blockIdx.x;
  int t = threadIdx.x;
  int g = bid / 3, rsub = bid - g * 3;

  if (rsub < 2) {
    // ---- GEMM path, gb in 0..2499 ----
    int gb = g * 2 + rsub;
    __bf16* As = ABs;
    __bf16* Bs = ABs + 64 * LSTR;
    int m0 = (gb >> 2) * 64;
    int n0 = (gb & 3) * 256;
    int w = t >> 6, l = t & 63;
    int lr = l & 15, lq = l >> 4;
    int ar = t >> 2, ac = (t & 3) * 8;   // A staging: row, col

    floatx4 acc[4][4] = {};              // [mt][nt]

    for (int ks = 0; ks < 8; ++ks) {
      const float* xp = x + (size_t)(m0 + ar) * 256 + ks * 32 + ac;
      float4 f0 = *(const float4*)xp;
      float4 f1 = *(const float4*)(xp + 4);
      bf16x8 av;
      av[0] = (__bf16)f0.x; av[1] = (__bf16)f0.y;
      av[2] = (__bf16)f0.z; av[3] = (__bf16)f0.w;
      av[4] = (__bf16)f1.x; av[5] = (__bf16)f1.y;
      av[6] = (__bf16)f1.z; av[7] = (__bf16)f1.w;
      const __bf16* wp = wt + (size_t)(n0 + t) * 256 + ks * 32;
      bf16x8 b0 = *(const bf16x8*)(wp);
      bf16x8 b1 = *(const bf16x8*)(wp + 8);
      bf16x8 b2 = *(const bf16x8*)(wp + 16);
      bf16x8 b3 = *(const bf16x8*)(wp + 24);
      __syncthreads();                   // previous step's frag reads done
      *(bf16x8*)&As[ar * LSTR + ac] = av;
      __bf16* bsr = &Bs[t * LSTR];
      *(bf16x8*)(bsr)      = b0;
      *(bf16x8*)(bsr + 8)  = b1;
      *(bf16x8*)(bsr + 16) = b2;
      *(bf16x8*)(bsr + 24) = b3;
      __syncthreads();
      bf16x8 af[4], bf_[4];
      #pragma unroll
      for (int mt = 0; mt < 4; ++mt)
        af[mt] = *(const bf16x8*)&As[(16 * mt + lr) * LSTR + lq * 8];
      #pragma unroll
      for (int nt = 0; nt < 4; ++nt)
        bf_[nt] = *(const bf16x8*)&Bs[(64 * w + 16 * nt + lr) * LSTR + lq * 8];
      #pragma unroll
      for (int mt = 0; mt < 4; ++mt)
        #pragma unroll
        for (int nt = 0; nt < 4; ++nt)
          acc[mt][nt] = __builtin_amdgcn_mfma_f32_16x16x32_bf16(af[mt], bf_[nt], acc[mt][nt], 0, 0, 0);
    }

    // C/D: col = lane&15, row = (lane>>4)*4 + reg
    #pragma unroll
    for (int mt = 0; mt < 4; ++mt)
      #pragma unroll
      for (int nt = 0; nt < 4; ++nt)
        #pragma unroll
        for (int r = 0; r < 4; ++r) {
          int gr = m0 + 16 * mt + lq * 4 + r;
          int gc = n0 + 64 * w + 16 * nt + lr;
          outq[(size_t)gr * 1024 + gc] = __float2bfloat16(acc[mt][nt][r] + bcat[gc]);
        }
  } else {
    // ---- esum path, g in 0..1249 ----
    float* wl = (float*)ABs;
    wl[t] = wesum[t];
    wl[t + 256] = wesum[t + 256];
    __syncthreads();
    int e = g * 256 + t;               // e < 320000 exactly
    float acc[8] = {};
    const float* row = edata + (size_t)e * 64;
    for (int d = 0; d < 64; d += 4) {
      float4 v = *(const float4*)(row + d);
      #pragma unroll
      for (int hh = 0; hh < 8; ++hh) {
        const float* wv = &wl[hh * 64 + d];
        acc[hh] += v.x * wv[0] + v.y * wv[1] + v.z * wv[2] + v.w * wv[3];
      }
    }
    float* op = esum + (size_t)pos[e] * 8;
    *(float4*)op       = make_float4(acc[0], acc[1], acc[2], acc[3]);
    *(float4*)(op + 4) = make_float4(acc[4], acc[5], acc[6], acc[7]);
  }
}

// ---------------------------------------------------------------------------
// Fused logits + softmax + V-aggregation + residual, fp32 out.
// ONE WAVE per dst node, BOTH batches: lane l owns channels 4l..4l+3 for
// b=0 and b=1 (head h = l>>3).
//  - ssrc read coalesced (src already in CSR order — no sorted->src gather).
//  - esum pre-sorted: streaming sequential read (no gather, no dep chain).
//  - two independent kv gather streams (b=0/b=1) x depth-2 prefetch = 4
//    dwordx4 in flight per wave for latency hiding.
//  - no online-max: logits bounded (|lg| << 88), exp() direct; loop-carried
//    deps are only the z/acc FMA accumulators.
// ---------------------------------------------------------------------------
__global__ __launch_bounds__(256) void aggregate_kernel(
    const unsigned int* __restrict__ qkvr,  // [MROWS][512] uints (kv | qr pairs)
    const float* __restrict__ esum,         // [E][8] CSR order
    const int* __restrict__ offsets,
    const int* __restrict__ ssrc,           // [E] src in CSR order
    float* __restrict__ out) {              // [MROWS][256] fp32
  int t = threadIdx.x;
  int w = t >> 6, l = t & 63;
  int n = blockIdx.x * 4 + w;               // grid 5000 -> 20000 waves
  int h = l >> 3;
  int beg = offsets[n], end = offsets[n + 1];

  uint4 qra = *(const uint4*)(qkvr + (size_t)(2 * n) * 512 + 256 + l * 4);
  uint4 qrb = *(const uint4*)(qkvr + (size_t)(2 * n + 1) * 512 + 256 + l * 4);
  float qa0 = __uint_as_float(qra.x << 16), qa1 = __uint_as_float(qra.y << 16);
  float qa2 = __uint_as_float(qra.z << 16), qa3 = __uint_as_float(qra.w << 16);
  float qb0 = __uint_as_float(qrb.x << 16), qb1 = __uint_as_float(qrb.y << 16);
  float qb2 = __uint_as_float(qrb.z << 16), qb3 = __uint_as_float(qrb.w << 16);

  const unsigned* kvl = qkvr + l * 4;       // + s*1024 (b=0), +512 more (b=1)

  float za = 0.f, zb = 0.f;
  float aa0 = 0.f, aa1 = 0.f, aa2 = 0.f, aa3 = 0.f;
  float ab0 = 0.f, ab1 = 0.f, ab2 = 0.f, ab3 = 0.f;

  for (int base = beg; base < end; base += 64) {
    int chunk = min(64, end - base);
    int s_l = (l < chunk) ? ssrc[base + l] : 0;
    const float* esp = esum + (size_t)base * 8 + h;
    uint4 kA0 = {0,0,0,0}, kA1 = {0,0,0,0};
    uint4 kB0 = {0,0,0,0}, kB1 = {0,0,0,0};
    float eA = 0.f, eB = 0.f;
    {
      int s0 = __builtin_amdgcn_readlane(s_l, 0);
      const unsigned* p = kvl + (size_t)s0 * 1024;
      kA0 = *(const uint4*)p;
      kA1 = *(const uint4*)(p + 512);
      eA = esp[0];
    }
    if (chunk > 1) {
      int s1 = __builtin_amdgcn_readlane(s_l, 1);
      const unsigned* p = kvl + (size_t)s1 * 1024;
      kB0 = *(const uint4*)p;
      kB1 = *(const uint4*)(p + 512);
      eB = esp[8];
    }
    for (int i = 0; i < chunk; ++i) {
      uint4 k0 = kA0, k1 = kA1; float es = eA;
      kA0 = kB0; kA1 = kB1; eA = eB;
      if (i + 2 < chunk) {
        int s2 = __builtin_amdgcn_readlane(s_l, i + 2);
        const unsigned* p = kvl + (size_t)s2 * 1024;
        kB0 = *(const uint4*)p;
        kB1 = *(const uint4*)(p + 512);
        eB = esp[(size_t)(i + 2) * 8];
      }
      float pa = __uint_as_float(k0.x << 16) * qa0
               + __uint_as_float(k0.y << 16) * qa1
               + __uint_as_float(k0.z << 16) * qa2
               + __uint_as_float(k0.w << 16) * qa3;
      float pb = __uint_as_float(k1.x << 16) * qb0
               + __uint_as_float(k1.y << 16) * qb1
               + __uint_as_float(k1.z << 16) * qb2
               + __uint_as_float(k1.w << 16) * qb3;
      pa += __shfl_xor(pa, 1, 64);  pb += __shfl_xor(pb, 1, 64);
      pa += __shfl_xor(pa, 2, 64);  pb += __shfl_xor(pb, 2, 64);
      pa += __shfl_xor(pa, 4, 64);  pb += __shfl_xor(pb, 4, 64);
      float ea_ = __expf(pa * 0.17677669529663687f + es);
      float eb_ = __expf(pb * 0.17677669529663687f + es);
      za += ea_; zb += eb_;
      aa0 += ea_ * __uint_as_float(k0.x & 0xFFFF0000u);
      aa1 += ea_ * __uint_as_float(k0.y & 0xFFFF0000u);
      aa2 += ea_ * __uint_as_float(k0.z & 0xFFFF0000u);
      aa3 += ea_ * __uint_as_float(k0.w & 0xFFFF0000u);
      ab0 += eb_ * __uint_as_float(k1.x & 0xFFFF0000u);
      ab1 += eb_ * __uint_as_float(k1.y & 0xFFFF0000u);
      ab2 += eb_ * __uint_as_float(k1.z & 0xFFFF0000u);
      ab3 += eb_ * __uint_as_float(k1.w & 0xFFFF0000u);
    }
  }
  float ia = (za > 0.f) ? 1.f / za : 0.f;
  float ib = (zb > 0.f) ? 1.f / zb : 0.f;
  float4 oa = make_float4(aa0 * ia + __uint_as_float(qra.x & 0xFFFF0000u),
                          aa1 * ia + __uint_as_float(qra.y & 0xFFFF0000u),
                          aa2 * ia + __uint_as_float(qra.z & 0xFFFF0000u),
                          aa3 * ia + __uint_as_float(qra.w & 0xFFFF0000u));
  float4 ob = make_float4(ab0 * ib + __uint_as_float(qrb.x & 0xFFFF0000u),
                          ab1 * ib + __uint_as_float(qrb.y & 0xFFFF0000u),
                          ab2 * ib + __uint_as_float(qrb.z & 0xFFFF0000u),
                          ab3 * ib + __uint_as_float(qrb.w & 0xFFFF0000u));
  *(float4*)(out + (size_t)(2 * n) * 256 + l * 4) = oa;
  *(float4*)(out + (size_t)(2 * n + 1) * 256 + l * 4) = ob;
}

// ---------------------------------------------------------------------------
extern "C" void kernel_launch(void* const* d_in, const int* in_sizes, int n_in,
                              void* d_out, int out_size, void* d_ws, size_t ws_size,
                              hipStream_t stream) {
  (void)in_sizes; (void)n_in; (void)out_size; (void)ws_size;
  const float* x     = (const float*)d_in[0];
  const float* edata = (const float*)d_in[1];
  const int* esrc    = (const int*)d_in[2];
  const int* edst    = (const int*)d_in[3];
  const float* Wq    = (const float*)d_in[4];
  const float* bq    = (const float*)d_in[5];
  const float* Wk    = (const float*)d_in[6];
  const float* bk    = (const float*)d_in[7];
  const float* Wv    = (const float*)d_in[8];
  const float* bv    = (const float*)d_in[9];
  const float* We    = (const float*)d_in[10];
  const float* Wr    = (const float*)d_in[11];
  const float* br    = (const float*)d_in[12];
  float* out = (float*)d_out;     // fp32 output

  char* ws = (char*)d_ws;
  size_t off = 0;
  auto carve = [&](size_t bytes) -> void* {
    void* p = ws + off;
    off += (bytes + 255) & ~(size_t)255;
    return p;
  };
  int* counts    = (int*)carve((size_t)NN * 4);
  int* offsets   = (int*)carve((size_t)(NN + 1) * 4);
  int* cursor    = (int*)carve((size_t)NN * 4);
  int* ssrc      = (int*)carve((size_t)EE * 4);               // 1.28 MB
  int* pos       = (int*)carve((size_t)EE * 4);               // 1.28 MB
  __hip_bfloat16* wt = (__hip_bfloat16*)carve((size_t)1024 * 256 * 2);
  float* bcat    = (float*)carve(1024 * 4);
  float* wesum   = (float*)carve(8 * 64 * 4);
  float* esum    = (float*)carve((size_t)EE * 8 * 4);         // 10.24 MB
  __hip_bfloat16* qkvr = (__hip_bfloat16*)carve((size_t)MROWS * 1024 * 2); // 81.9 MB

  zero_ints<<<(NN + 255) / 256, 256, 0, stream>>>(counts, NN);
  transpose_weights<<<16, 256, 0, stream>>>(Wq, Wk, Wv, Wr, wt);
  prep_bias<<<4, 256, 0, stream>>>(bq, bk, bv, br, bcat);
  prep_wesum<<<1, 512, 0, stream>>>(We, wesum);
  hist_kernel<<<(EE + 255) / 256, 256, 0, stream>>>(edst, counts);
  scan_kernel<<<1, 256, 0, stream>>>(counts, offsets, cursor);
  scatter_kernel<<<(EE + 255) / 256, 256, 0, stream>>>(edst, esrc, cursor, ssrc, pos);
  fused_gemm_esum<<<3750, 256, 0, stream>>>(x, (const __bf16*)wt, bcat, qkvr,
                                            edata, wesum, pos, esum);
  aggregate_kernel<<<NN / 4, 256, 0, stream>>>((const unsigned int*)qkvr, esum,
                                               offsets, ssrc, out);
}

// Round 3
// 428.034 us; speedup vs baseline: 1.2182x; 1.0479x over previous
//
#include <hip/hip_runtime.h>
#include <hip/hip_bf16.h>

#define NN    20000
#define BB    2
#define EE    320000
#define MROWS (NN * BB)   // 40000

typedef __bf16 bf16x8 __attribute__((ext_vector_type(8)));
typedef float  floatx4 __attribute__((ext_vector_type(4)));

// Channel permutation of the 1024 fused output channels (c = head*32+chan):
//   j in [0,512):    c = j>>1;        j even -> k[c], j odd -> v[c]
//   j in [512,1024): c = (j-512)>>1;  j even -> q[c], j odd -> r[c]
// So a uint32 at row*512 + c       = (k[c] | v[c]<<16)  (bf16 pair)
//    a uint32 at row*512 + 256 + c = (q[c] | r[c]<<16)

// ---------------------------------------------------------------------------
// Merged prep: blocks 0..15 = weight transpose+permute, block 16 = bias+wesum,
// blocks 17.. = dst histogram. (counts zeroed by hipMemsetAsync beforehand.)
// ---------------------------------------------------------------------------
__global__ __launch_bounds__(256) void prep_kernel(
    const float* __restrict__ Wq, const float* __restrict__ Wk,
    const float* __restrict__ Wv, const float* __restrict__ Wr,
    __hip_bfloat16* __restrict__ wt,
    const float* __restrict__ bq, const float* __restrict__ bk,
    const float* __restrict__ bv, const float* __restrict__ br,
    float* __restrict__ bcat,
    const float* __restrict__ We, float* __restrict__ wesum,
    const int* __restrict__ edst, int* __restrict__ counts) {
  __shared__ float TA[32][65];
  __shared__ float TB[32][65];
  int bt = blockIdx.x;
  int t = threadIdx.x;

  if (bt < 16) {
    const float *A, *B;
    int c0, jbase;
    if (bt < 8) { A = Wk; B = Wv; c0 = 32 * bt;      jbase = 64 * bt; }
    else        { A = Wq; B = Wr; c0 = 32 * (bt-8);  jbase = 512 + 64 * (bt-8); }
    int krow = t >> 2;                   // 0..63
    int cc = (t & 3) * 8;                // 0,8,16,24
    int sel = t >> 7;                    // write phase: 0->A, 1->B
    int u = t & 127;
    int ci = u >> 2;                     // 0..31
    int kk0 = (u & 3) * 16;              // 0,16,32,48

    for (int kt = 0; kt < 4; ++kt) {
      int k = kt * 64 + krow;
      float4 a0 = *(const float4*)(A + (size_t)k * 256 + c0 + cc);
      float4 a1 = *(const float4*)(A + (size_t)k * 256 + c0 + cc + 4);
      float4 b0 = *(const float4*)(B + (size_t)k * 256 + c0 + cc);
      float4 b1 = *(const float4*)(B + (size_t)k * 256 + c0 + cc + 4);
      __syncthreads();                   // previous write phase done
      TA[cc+0][krow]=a0.x; TA[cc+1][krow]=a0.y; TA[cc+2][krow]=a0.z; TA[cc+3][krow]=a0.w;
      TA[cc+4][krow]=a1.x; TA[cc+5][krow]=a1.y; TA[cc+6][krow]=a1.z; TA[cc+7][krow]=a1.w;
      TB[cc+0][krow]=b0.x; TB[cc+1][krow]=b0.y; TB[cc+2][krow]=b0.z; TB[cc+3][krow]=b0.w;
      TB[cc+4][krow]=b1.x; TB[cc+5][krow]=b1.y; TB[cc+6][krow]=b1.z; TB[cc+7][krow]=b1.w;
      __syncthreads();
      float (*T)[65] = sel ? TB : TA;
      int j = jbase + 2 * ci + sel;
      __hip_bfloat16* dst = wt + (size_t)j * 256 + kt * 64 + kk0;
      #pragma unroll
      for (int q = 0; q < 16; ++q) dst[q] = __float2bfloat16(T[ci][kk0 + q]);
    }
  } else if (bt == 16) {
    #pragma unroll
    for (int jj = 0; jj < 4; ++jj) {
      int j = jj * 256 + t;
      float val;
      if (j < 512) { int c = j >> 1;         val = (j & 1) ? bv[c] : bk[c]; }
      else         { int c = (j - 512) >> 1; val = (j & 1) ? br[c] : bq[c]; }
      bcat[j] = val;
    }
    #pragma unroll
    for (int ii = 0; ii < 2; ++ii) {
      int i = ii * 256 + t;
      int h = i >> 6, d = i & 63;
      float s = 0.f;
      for (int c = 0; c < 32; ++c) s += We[(size_t)d * 256 + h * 32 + c];
      wesum[h * 64 + d] = s;
    }
  } else {
    int e = (bt - 17) * 256 + t;
    if (e < EE) atomicAdd(&counts[edst[e]], 1);
  }
}

// ---------------------------------------------------------------------------
// 1-block scan of counts -> offsets, cursor
// ---------------------------------------------------------------------------
__global__ void scan_kernel(const int* __restrict__ counts,
                            int* __restrict__ offsets,
                            int* __restrict__ cursor) {
  __shared__ int part[256];
  int t = threadIdx.x;
  const int per = (NN + 255) / 256;   // 79
  int lo = t * per, hi = min(lo + per, NN);
  int s = 0;
  #pragma unroll 4
  for (int i = lo; i < hi; ++i) s += counts[i];
  part[t] = s;
  __syncthreads();
  for (int off = 1; off < 256; off <<= 1) {
    int v = (t >= off) ? part[t - off] : 0;
    __syncthreads();
    part[t] += v;
    __syncthreads();
  }
  int base = (t == 0) ? 0 : part[t - 1];
  for (int i = lo; i < hi; ++i) {
    offsets[i] = base;
    cursor[i] = base;
    base += counts[i];
  }
  if (t == 255) offsets[NN] = base;
}

// ---------------------------------------------------------------------------
// Fused scatter + edge-feature reduction: one pass over the edge list.
// Each edge grabs its CSR slot p, writes src there (coalesced read later in
// aggregate) and writes esum[p][h] = edata[e].wesum[h] directly pre-sorted.
// Edge order within a dst is nondeterministic -> softmax is permutation-
// invariant, fine.
// ---------------------------------------------------------------------------
__global__ __launch_bounds__(256) void scatter_esum(
    const int* __restrict__ edst, const int* __restrict__ esrc,
    int* __restrict__ cursor,
    const float* __restrict__ edata, const float* __restrict__ wesum,
    int* __restrict__ ssrc, float* __restrict__ esum) {
  __shared__ float wl[512];
  int t = threadIdx.x;
  wl[t] = wesum[t];
  wl[t + 256] = wesum[t + 256];
  __syncthreads();
  int e = blockIdx.x * 256 + t;        // EE = 1250*256 exactly
  int p = atomicAdd(&cursor[edst[e]], 1);
  ssrc[p] = esrc[e];
  float acc[8] = {};
  const float* row = edata + (size_t)e * 64;
  for (int d = 0; d < 64; d += 4) {
    float4 v = *(const float4*)(row + d);
    #pragma unroll
    for (int hh = 0; hh < 8; ++hh) {
      const float* wv = &wl[hh * 64 + d];
      acc[hh] += v.x * wv[0] + v.y * wv[1] + v.z * wv[2] + v.w * wv[3];
    }
  }
  float* op = esum + (size_t)p * 8;
  *(float4*)op       = make_float4(acc[0], acc[1], acc[2], acc[3]);
  *(float4*)(op + 4) = make_float4(acc[4], acc[5], acc[6], acc[7]);
}

// ---------------------------------------------------------------------------
// Fused q|k|v|r GEMM, channel-permuted bf16 output (standalone again —
// round-2 fusion with esum regressed it: MfmaUtil 6%, occupancy 20%).
// Tile M=64 x N=256, BK=32, 4 waves each 64x64 (4x4 frags).
// LDS row stride 40 elems: 16B-aligned frag reads, ~2-way banks (free).
// ---------------------------------------------------------------------------
__global__ __launch_bounds__(256) void gemm_qkvr(
    const float* __restrict__ x,     // [MROWS][256] fp32
    const __bf16* __restrict__ wt,   // [1024][256] bf16 (n-major, permuted)
    const float* __restrict__ bcat,  // [1024] permuted
    __hip_bfloat16* __restrict__ out) {  // [MROWS][1024] bf16 permuted
  const int LSTR = 40;
  __shared__ __attribute__((aligned(16))) __bf16 As[64 * LSTR];
  __shared__ __attribute__((aligned(16))) __bf16 Bs[256 * LSTR];

  int m0 = blockIdx.y * 64;
  int n0 = blockIdx.x * 256;
  int t = threadIdx.x;
  int w = t >> 6, l = t & 63;
  int lr = l & 15, lq = l >> 4;
  int ar = t >> 2, ac = (t & 3) * 8;   // A staging: row, col

  floatx4 acc[4][4] = {};              // [mt][nt]

  for (int ks = 0; ks < 8; ++ks) {
    const float* xp = x + (size_t)(m0 + ar) * 256 + ks * 32 + ac;
    float4 f0 = *(const float4*)xp;
    float4 f1 = *(const float4*)(xp + 4);
    bf16x8 av;
    av[0] = (__bf16)f0.x; av[1] = (__bf16)f0.y;
    av[2] = (__bf16)f0.z; av[3] = (__bf16)f0.w;
    av[4] = (__bf16)f1.x; av[5] = (__bf16)f1.y;
    av[6] = (__bf16)f1.z; av[7] = (__bf16)f1.w;
    const __bf16* wp = wt + (size_t)(n0 + t) * 256 + ks * 32;
    bf16x8 b0 = *(const bf16x8*)(wp);
    bf16x8 b1 = *(const bf16x8*)(wp + 8);
    bf16x8 b2 = *(const bf16x8*)(wp + 16);
    bf16x8 b3 = *(const bf16x8*)(wp + 24);
    __syncthreads();                   // previous step's frag reads done
    *(bf16x8*)&As[ar * LSTR + ac] = av;
    __bf16* bsr = &Bs[t * LSTR];
    *(bf16x8*)(bsr)      = b0;
    *(bf16x8*)(bsr + 8)  = b1;
    *(bf16x8*)(bsr + 16) = b2;
    *(bf16x8*)(bsr + 24) = b3;
    __syncthreads();
    bf16x8 af[4], bf_[4];
    #pragma unroll
    for (int mt = 0; mt < 4; ++mt)
      af[mt] = *(const bf16x8*)&As[(16 * mt + lr) * LSTR + lq * 8];
    #pragma unroll
    for (int nt = 0; nt < 4; ++nt)
      bf_[nt] = *(const bf16x8*)&Bs[(64 * w + 16 * nt + lr) * LSTR + lq * 8];
    #pragma unroll
    for (int mt = 0; mt < 4; ++mt)
      #pragma unroll
      for (int nt = 0; nt < 4; ++nt)
        acc[mt][nt] = __builtin_amdgcn_mfma_f32_16x16x32_bf16(af[mt], bf_[nt], acc[mt][nt], 0, 0, 0);
  }

  // C/D: col = lane&15, row = (lane>>4)*4 + reg
  #pragma unroll
  for (int mt = 0; mt < 4; ++mt)
    #pragma unroll
    for (int nt = 0; nt < 4; ++nt)
      #pragma unroll
      for (int r = 0; r < 4; ++r) {
        int gr = m0 + 16 * mt + lq * 4 + r;
        int gc = n0 + 64 * w + 16 * nt + lr;
        out[(size_t)gr * 1024 + gc] = __float2bfloat16(acc[mt][nt][r] + bcat[gc]);
      }
}

// ---------------------------------------------------------------------------
// Fused logits + softmax + V-aggregation + residual, fp32 out.
// ONE WAVE per dst node, BOTH batches; lane l owns channels 4l..4l+3.
// 4-slot software pipeline, prefetch distance 4, no register rotation
// (slots consumed in place; all pipeline guards are wave-uniform).
// 8 dwordx4 kv-gathers + 4 esum loads in flight per wave.
// ---------------------------------------------------------------------------
#define LOADSLOT(K0, K1, EV, IDX)                                    \
  { int s_ = __builtin_amdgcn_readlane(s_l, (IDX));                  \
    const unsigned* p_ = kvl + (size_t)s_ * 1024;                    \
    K0 = *(const uint4*)p_;                                          \
    K1 = *(const uint4*)(p_ + 512);                                  \
    EV = esp[(size_t)(IDX) * 8]; }

#define CONSUME(K0, K1, EV)                                          \
  { float pa = __uint_as_float(K0.x << 16) * qa0                     \
             + __uint_as_float(K0.y << 16) * qa1                     \
             + __uint_as_float(K0.z << 16) * qa2                     \
             + __uint_as_float(K0.w << 16) * qa3;                    \
    float pb = __uint_as_float(K1.x << 16) * qb0                     \
             + __uint_as_float(K1.y << 16) * qb1                     \
             + __uint_as_float(K1.z << 16) * qb2                     \
             + __uint_as_float(K1.w << 16) * qb3;                    \
    pa += __shfl_xor(pa, 1, 64);  pb += __shfl_xor(pb, 1, 64);       \
    pa += __shfl_xor(pa, 2, 64);  pb += __shfl_xor(pb, 2, 64);       \
    pa += __shfl_xor(pa, 4, 64);  pb += __shfl_xor(pb, 4, 64);       \
    float ea_ = __expf(pa * 0.17677669529663687f + EV);              \
    float eb_ = __expf(pb * 0.17677669529663687f + EV);              \
    za += ea_; zb += eb_;                                            \
    aa0 += ea_ * __uint_as_float(K0.x & 0xFFFF0000u);                \
    aa1 += ea_ * __uint_as_float(K0.y & 0xFFFF0000u);                \
    aa2 += ea_ * __uint_as_float(K0.z & 0xFFFF0000u);                \
    aa3 += ea_ * __uint_as_float(K0.w & 0xFFFF0000u);                \
    ab0 += eb_ * __uint_as_float(K1.x & 0xFFFF0000u);                \
    ab1 += eb_ * __uint_as_float(K1.y & 0xFFFF0000u);                \
    ab2 += eb_ * __uint_as_float(K1.z & 0xFFFF0000u);                \
    ab3 += eb_ * __uint_as_float(K1.w & 0xFFFF0000u); }

__global__ __launch_bounds__(256) void aggregate_kernel(
    const unsigned int* __restrict__ qkvr,  // [MROWS][512] uints (kv | qr pairs)
    const float* __restrict__ esum,         // [E][8] CSR order
    const int* __restrict__ offsets,
    const int* __restrict__ ssrc,           // [E] src in CSR order
    float* __restrict__ out) {              // [MROWS][256] fp32
  int t = threadIdx.x;
  int w = t >> 6, l = t & 63;
  int n = blockIdx.x * 4 + w;               // grid 5000 -> 20000 waves
  int h = l >> 3;
  int beg = offsets[n], end = offsets[n + 1];

  uint4 qra = *(const uint4*)(qkvr + (size_t)(2 * n) * 512 + 256 + l * 4);
  uint4 qrb = *(const uint4*)(qkvr + (size_t)(2 * n + 1) * 512 + 256 + l * 4);
  float qa0 = __uint_as_float(qra.x << 16), qa1 = __uint_as_float(qra.y << 16);
  float qa2 = __uint_as_float(qra.z << 16), qa3 = __uint_as_float(qra.w << 16);
  float qb0 = __uint_as_float(qrb.x << 16), qb1 = __uint_as_float(qrb.y << 16);
  float qb2 = __uint_as_float(qrb.z << 16), qb3 = __uint_as_float(qrb.w << 16);

  const unsigned* kvl = qkvr + l * 4;       // + s*1024 (b=0), +512 more (b=1)

  float za = 0.f, zb = 0.f;
  float aa0 = 0.f, aa1 = 0.f, aa2 = 0.f, aa3 = 0.f;
  float ab0 = 0.f, ab1 = 0.f, ab2 = 0.f, ab3 = 0.f;

  for (int base = beg; base < end; base += 64) {
    int chunk = min(64, end - base);
    int s_l = (l < chunk) ? ssrc[base + l] : 0;
    const float* esp = esum + (size_t)base * 8 + h;
    uint4 kA0 = {0,0,0,0}, kA1 = {0,0,0,0}, kB0 = {0,0,0,0}, kB1 = {0,0,0,0};
    uint4 kC0 = {0,0,0,0}, kC1 = {0,0,0,0}, kD0 = {0,0,0,0}, kD1 = {0,0,0,0};
    float eA = 0.f, eB = 0.f, eC = 0.f, eD = 0.f;
    LOADSLOT(kA0, kA1, eA, 0);
    if (chunk > 1) LOADSLOT(kB0, kB1, eB, 1);
    if (chunk > 2) LOADSLOT(kC0, kC1, eC, 2);
    if (chunk > 3) LOADSLOT(kD0, kD1, eD, 3);
    for (int i = 0; i < chunk; i += 4) {
      CONSUME(kA0, kA1, eA);
      if (i + 4 < chunk) LOADSLOT(kA0, kA1, eA, i + 4);
      if (i + 1 < chunk) {
        CONSUME(kB0, kB1, eB);
        if (i + 5 < chunk) LOADSLOT(kB0, kB1, eB, i + 5);
        if (i + 2 < chunk) {
          CONSUME(kC0, kC1, eC);
          if (i + 6 < chunk) LOADSLOT(kC0, kC1, eC, i + 6);
          if (i + 3 < chunk) {
            CONSUME(kD0, kD1, eD);
            if (i + 7 < chunk) LOADSLOT(kD0, kD1, eD, i + 7);
          }
        }
      }
    }
  }
  float ia = (za > 0.f) ? 1.f / za : 0.f;
  float ib = (zb > 0.f) ? 1.f / zb : 0.f;
  float4 oa = make_float4(aa0 * ia + __uint_as_float(qra.x & 0xFFFF0000u),
                          aa1 * ia + __uint_as_float(qra.y & 0xFFFF0000u),
                          aa2 * ia + __uint_as_float(qra.z & 0xFFFF0000u),
                          aa3 * ia + __uint_as_float(qra.w & 0xFFFF0000u));
  float4 ob = make_float4(ab0 * ib + __uint_as_float(qrb.x & 0xFFFF0000u),
                          ab1 * ib + __uint_as_float(qrb.y & 0xFFFF0000u),
                          ab2 * ib + __uint_as_float(qrb.z & 0xFFFF0000u),
                          ab3 * ib + __uint_as_float(qrb.w & 0xFFFF0000u));
  *(float4*)(out + (size_t)(2 * n) * 256 + l * 4) = oa;
  *(float4*)(out + (size_t)(2 * n + 1) * 256 + l * 4) = ob;
}

// ---------------------------------------------------------------------------
extern "C" void kernel_launch(void* const* d_in, const int* in_sizes, int n_in,
                              void* d_out, int out_size, void* d_ws, size_t ws_size,
                              hipStream_t stream) {
  (void)in_sizes; (void)n_in; (void)out_size; (void)ws_size;
  const float* x     = (const float*)d_in[0];
  const float* edata = (const float*)d_in[1];
  const int* esrc    = (const int*)d_in[2];
  const int* edst    = (const int*)d_in[3];
  const float* Wq    = (const float*)d_in[4];
  const float* bq    = (const float*)d_in[5];
  const float* Wk    = (const float*)d_in[6];
  const float* bk    = (const float*)d_in[7];
  const float* Wv    = (const float*)d_in[8];
  const float* bv    = (const float*)d_in[9];
  const float* We    = (const float*)d_in[10];
  const float* Wr    = (const float*)d_in[11];
  const float* br    = (const float*)d_in[12];
  float* out = (float*)d_out;     // fp32 output

  char* ws = (char*)d_ws;
  size_t off = 0;
  auto carve = [&](size_t bytes) -> void* {
    void* p = ws + off;
    off += (bytes + 255) & ~(size_t)255;
    return p;
  };
  int* counts    = (int*)carve((size_t)NN * 4);
  int* offsets   = (int*)carve((size_t)(NN + 1) * 4);
  int* cursor    = (int*)carve((size_t)NN * 4);
  int* ssrc      = (int*)carve((size_t)EE * 4);               // 1.28 MB
  __hip_bfloat16* wt = (__hip_bfloat16*)carve((size_t)1024 * 256 * 2);
  float* bcat    = (float*)carve(1024 * 4);
  float* wesum   = (float*)carve(8 * 64 * 4);
  float* esum    = (float*)carve((size_t)EE * 8 * 4);         // 10.24 MB
  __hip_bfloat16* qkvr = (__hip_bfloat16*)carve((size_t)MROWS * 1024 * 2); // 81.9 MB

  hipMemsetAsync(counts, 0, (size_t)NN * 4, stream);
  prep_kernel<<<17 + (EE + 255) / 256, 256, 0, stream>>>(
      Wq, Wk, Wv, Wr, wt, bq, bk, bv, br, bcat, We, wesum, edst, counts);
  scan_kernel<<<1, 256, 0, stream>>>(counts, offsets, cursor);
  scatter_esum<<<EE / 256, 256, 0, stream>>>(edst, esrc, cursor, edata, wesum,
                                             ssrc, esum);
  gemm_qkvr<<<dim3(4, 625), 256, 0, stream>>>(x, (const __bf16*)wt, bcat, qkvr);
  aggregate_kernel<<<NN / 4, 256, 0, stream>>>((const unsigned int*)qkvr, esum,
                                               offsets, ssrc, out);
}

// Round 4
// 416.832 us; speedup vs baseline: 1.2510x; 1.0269x over previous
//
#include <hip/hip_runtime.h>
#include <hip/hip_bf16.h>

#define NN    20000
#define BB    2
#define EE    320000
#define MROWS (NN * BB)   // 40000

typedef __bf16 bf16x8 __attribute__((ext_vector_type(8)));
typedef __bf16 bf16x4 __attribute__((ext_vector_type(4)));
typedef float  floatx4 __attribute__((ext_vector_type(4)));

// Channel permutation of the 1024 fused output channels (c = head*32+chan):
//   j in [0,512):    c = j>>1;        j even -> k[c], j odd -> v[c]
//   j in [512,1024): c = (j-512)>>1;  j even -> q[c], j odd -> r[c]
// So a uint32 at row*512 + c       = (k[c] | v[c]<<16)  (bf16 pair)
//    a uint32 at row*512 + 256 + c = (q[c] | r[c]<<16)

#define NB_HIST 1250   // (EE+255)/256
#define NB_CVT  1250   // MROWS*256 / 8192

// ---------------------------------------------------------------------------
// Merged prep: blocks 0..15 weight transpose+permute, 16 bias+wesum,
// 17..1266 dst histogram, 1267..2516 x -> bf16 convert.
// (counts zeroed by hipMemsetAsync beforehand.)
// ---------------------------------------------------------------------------
__global__ __launch_bounds__(256) void prep_kernel(
    const float* __restrict__ Wq, const float* __restrict__ Wk,
    const float* __restrict__ Wv, const float* __restrict__ Wr,
    __hip_bfloat16* __restrict__ wt,
    const float* __restrict__ bq, const float* __restrict__ bk,
    const float* __restrict__ bv, const float* __restrict__ br,
    float* __restrict__ bcat,
    const float* __restrict__ We, float* __restrict__ wesum,
    const int* __restrict__ edst, int* __restrict__ counts,
    const float* __restrict__ x, __bf16* __restrict__ xb) {
  __shared__ float TA[32][65];
  __shared__ float TB[32][65];
  int bt = blockIdx.x;
  int t = threadIdx.x;

  if (bt < 16) {
    const float *A, *B;
    int c0, jbase;
    if (bt < 8) { A = Wk; B = Wv; c0 = 32 * bt;      jbase = 64 * bt; }
    else        { A = Wq; B = Wr; c0 = 32 * (bt-8);  jbase = 512 + 64 * (bt-8); }
    int krow = t >> 2;                   // 0..63
    int cc = (t & 3) * 8;                // 0,8,16,24
    int sel = t >> 7;                    // write phase: 0->A, 1->B
    int u = t & 127;
    int ci = u >> 2;                     // 0..31
    int kk0 = (u & 3) * 16;              // 0,16,32,48

    for (int kt = 0; kt < 4; ++kt) {
      int k = kt * 64 + krow;
      float4 a0 = *(const float4*)(A + (size_t)k * 256 + c0 + cc);
      float4 a1 = *(const float4*)(A + (size_t)k * 256 + c0 + cc + 4);
      float4 b0 = *(const float4*)(B + (size_t)k * 256 + c0 + cc);
      float4 b1 = *(const float4*)(B + (size_t)k * 256 + c0 + cc + 4);
      __syncthreads();                   // previous write phase done
      TA[cc+0][krow]=a0.x; TA[cc+1][krow]=a0.y; TA[cc+2][krow]=a0.z; TA[cc+3][krow]=a0.w;
      TA[cc+4][krow]=a1.x; TA[cc+5][krow]=a1.y; TA[cc+6][krow]=a1.z; TA[cc+7][krow]=a1.w;
      TB[cc+0][krow]=b0.x; TB[cc+1][krow]=b0.y; TB[cc+2][krow]=b0.z; TB[cc+3][krow]=b0.w;
      TB[cc+4][krow]=b1.x; TB[cc+5][krow]=b1.y; TB[cc+6][krow]=b1.z; TB[cc+7][krow]=b1.w;
      __syncthreads();
      float (*T)[65] = sel ? TB : TA;
      int j = jbase + 2 * ci + sel;
      __hip_bfloat16* dst = wt + (size_t)j * 256 + kt * 64 + kk0;
      #pragma unroll
      for (int q = 0; q < 16; ++q) dst[q] = __float2bfloat16(T[ci][kk0 + q]);
    }
  } else if (bt == 16) {
    #pragma unroll
    for (int jj = 0; jj < 4; ++jj) {
      int j = jj * 256 + t;
      float val;
      if (j < 512) { int c = j >> 1;         val = (j & 1) ? bv[c] : bk[c]; }
      else         { int c = (j - 512) >> 1; val = (j & 1) ? br[c] : bq[c]; }
      bcat[j] = val;
    }
    #pragma unroll
    for (int ii = 0; ii < 2; ++ii) {
      int i = ii * 256 + t;
      int h = i >> 6, d = i & 63;
      float s = 0.f;
      for (int c = 0; c < 32; ++c) s += We[(size_t)d * 256 + h * 32 + c];
      wesum[h * 64 + d] = s;
    }
  } else if (bt < 17 + NB_HIST) {
    int e = (bt - 17) * 256 + t;
    if (e < EE) atomicAdd(&counts[edst[e]], 1);
  } else {
    int cb = bt - 17 - NB_HIST;          // 0..1249
    size_t base = (size_t)cb * 8192 + t * 4;
    #pragma unroll
    for (int j = 0; j < 8; ++j) {
      float4 v = *(const float4*)(x + base + j * 1024);
      bf16x4 o;
      o[0] = (__bf16)v.x; o[1] = (__bf16)v.y;
      o[2] = (__bf16)v.z; o[3] = (__bf16)v.w;
      *(bf16x4*)(xb + base + j * 1024) = o;
    }
  }
}

// ---------------------------------------------------------------------------
// 1-block scan of counts -> offsets, cursor
// ---------------------------------------------------------------------------
__global__ void scan_kernel(const int* __restrict__ counts,
                            int* __restrict__ offsets,
                            int* __restrict__ cursor) {
  __shared__ int part[256];
  int t = threadIdx.x;
  const int per = (NN + 255) / 256;   // 79
  int lo = t * per, hi = min(lo + per, NN);
  int s = 0;
  #pragma unroll 4
  for (int i = lo; i < hi; ++i) s += counts[i];
  part[t] = s;
  __syncthreads();
  for (int off = 1; off < 256; off <<= 1) {
    int v = (t >= off) ? part[t - off] : 0;
    __syncthreads();
    part[t] += v;
    __syncthreads();
  }
  int base = (t == 0) ? 0 : part[t - 1];
  for (int i = lo; i < hi; ++i) {
    offsets[i] = base;
    cursor[i] = base;
    base += counts[i];
  }
  if (t == 255) offsets[NN] = base;
}

// ---------------------------------------------------------------------------
// Fused scatter + edge-feature reduction: one pass over the edge list.
// Each edge grabs its CSR slot p, writes src there (coalesced read later in
// aggregate) and writes esum[p][h] = edata[e].wesum[h] directly pre-sorted.
// ---------------------------------------------------------------------------
__global__ __launch_bounds__(256) void scatter_esum(
    const int* __restrict__ edst, const int* __restrict__ esrc,
    int* __restrict__ cursor,
    const float* __restrict__ edata, const float* __restrict__ wesum,
    int* __restrict__ ssrc, float* __restrict__ esum) {
  __shared__ float wl[512];
  int t = threadIdx.x;
  wl[t] = wesum[t];
  wl[t + 256] = wesum[t + 256];
  __syncthreads();
  int e = blockIdx.x * 256 + t;        // EE = 1250*256 exactly
  int p = atomicAdd(&cursor[edst[e]], 1);
  ssrc[p] = esrc[e];
  float acc[8] = {};
  const float* row = edata + (size_t)e * 64;
  for (int d = 0; d < 64; d += 4) {
    float4 v = *(const float4*)(row + d);
    #pragma unroll
    for (int hh = 0; hh < 8; ++hh) {
      const float* wv = &wl[hh * 64 + d];
      acc[hh] += v.x * wv[0] + v.y * wv[1] + v.z * wv[2] + v.w * wv[3];
    }
  }
  float* op = esum + (size_t)p * 8;
  *(float4*)op       = make_float4(acc[0], acc[1], acc[2], acc[3]);
  *(float4*)(op + 4) = make_float4(acc[4], acc[5], acc[6], acc[7]);
}

// ---------------------------------------------------------------------------
// Fused q|k|v|r GEMM, channel-permuted bf16 output. A input pre-converted
// to bf16 (xb): no per-K-step cvt chain. BK=64 -> 4 K-steps (half the
// barriers of BK=32). Tile 64x256, 4 waves each 64x64 (4x4 frags).
// LSTR=72 elems (144 B): 16B-aligned frag reads, 2-way banks (free, m136).
// 16 MFMA per 8 ds_read_b128 per kk-pass (m97 ratio). LDS 46 KB -> 3 blk/CU.
// ---------------------------------------------------------------------------
__global__ __launch_bounds__(256) void gemm_qkvr(
    const __bf16* __restrict__ xb,   // [MROWS][256] bf16
    const __bf16* __restrict__ wt,   // [1024][256] bf16 (n-major, permuted)
    const float* __restrict__ bcat,  // [1024] permuted
    __hip_bfloat16* __restrict__ out) {  // [MROWS][1024] bf16 permuted
  const int LSTR = 72;
  __shared__ __attribute__((aligned(16))) __bf16 As[64 * LSTR];
  __shared__ __attribute__((aligned(16))) __bf16 Bs[256 * LSTR];

  int m0 = blockIdx.y * 64;
  int n0 = blockIdx.x * 256;
  int t = threadIdx.x;
  int w = t >> 6, l = t & 63;
  int lr = l & 15, lq = l >> 4;
  int ar = t >> 2, ac = (t & 3) * 16;   // A staging: row, col (16 elems/thr)

  floatx4 acc[4][4] = {};               // [mt][nt]

  for (int ks = 0; ks < 4; ++ks) {
    const __bf16* xp = xb + (size_t)(m0 + ar) * 256 + ks * 64 + ac;
    bf16x8 a0 = *(const bf16x8*)xp;
    bf16x8 a1 = *(const bf16x8*)(xp + 8);
    const __bf16* wp = wt + (size_t)(n0 + t) * 256 + ks * 64;
    bf16x8 b0 = *(const bf16x8*)(wp);
    bf16x8 b1 = *(const bf16x8*)(wp + 8);
    bf16x8 b2 = *(const bf16x8*)(wp + 16);
    bf16x8 b3 = *(const bf16x8*)(wp + 24);
    bf16x8 b4 = *(const bf16x8*)(wp + 32);
    bf16x8 b5 = *(const bf16x8*)(wp + 40);
    bf16x8 b6 = *(const bf16x8*)(wp + 48);
    bf16x8 b7 = *(const bf16x8*)(wp + 56);
    __syncthreads();                    // previous step's frag reads done
    *(bf16x8*)&As[ar * LSTR + ac]     = a0;
    *(bf16x8*)&As[ar * LSTR + ac + 8] = a1;
    __bf16* bsr = &Bs[t * LSTR];
    *(bf16x8*)(bsr)      = b0;
    *(bf16x8*)(bsr + 8)  = b1;
    *(bf16x8*)(bsr + 16) = b2;
    *(bf16x8*)(bsr + 24) = b3;
    *(bf16x8*)(bsr + 32) = b4;
    *(bf16x8*)(bsr + 40) = b5;
    *(bf16x8*)(bsr + 48) = b6;
    *(bf16x8*)(bsr + 56) = b7;
    __syncthreads();
    #pragma unroll
    for (int kk = 0; kk < 2; ++kk) {
      bf16x8 af[4], bf_[4];
      #pragma unroll
      for (int mt = 0; mt < 4; ++mt)
        af[mt] = *(const bf16x8*)&As[(16 * mt + lr) * LSTR + kk * 32 + lq * 8];
      #pragma unroll
      for (int nt = 0; nt < 4; ++nt)
        bf_[nt] = *(const bf16x8*)&Bs[(64 * w + 16 * nt + lr) * LSTR + kk * 32 + lq * 8];
      #pragma unroll
      for (int mt = 0; mt < 4; ++mt)
        #pragma unroll
        for (int nt = 0; nt < 4; ++nt)
          acc[mt][nt] = __builtin_amdgcn_mfma_f32_16x16x32_bf16(af[mt], bf_[nt], acc[mt][nt], 0, 0, 0);
    }
  }

  // C/D: col = lane&15, row = (lane>>4)*4 + reg
  #pragma unroll
  for (int mt = 0; mt < 4; ++mt)
    #pragma unroll
    for (int nt = 0; nt < 4; ++nt)
      #pragma unroll
      for (int r = 0; r < 4; ++r) {
        int gr = m0 + 16 * mt + lq * 4 + r;
        int gc = n0 + 64 * w + 16 * nt + lr;
        out[(size_t)gr * 1024 + gc] = __float2bfloat16(acc[mt][nt][r] + bcat[gc]);
      }
}

// ---------------------------------------------------------------------------
// Fused logits + softmax + V-aggregation + residual, fp32 out.
// ONE WAVE per (dst,b) — 40000 waves for max TLP; lane l owns channels
// 4l..4l+3 (head h = l>>3). Depth-6 software pipeline, no register rotation:
// 6 dwordx4 kv-gathers + 6 esum loads in flight per wave; all guards
// wave-uniform. No online-max (logits bounded, exp() direct).
// ---------------------------------------------------------------------------
#define LOADSLOT(KV, EV, IDX)                                        \
  { int s_ = __builtin_amdgcn_readlane(s_l, (IDX));                  \
    KV = *(const uint4*)(kvl + (size_t)s_ * 1024);                   \
    EV = esp[(size_t)(IDX) * 8]; }

#define CONSUME(KV, EV)                                              \
  { float part = __uint_as_float(KV.x << 16) * q0                    \
               + __uint_as_float(KV.y << 16) * q1                    \
               + __uint_as_float(KV.z << 16) * q2                    \
               + __uint_as_float(KV.w << 16) * q3;                   \
    part += __shfl_xor(part, 1, 64);                                 \
    part += __shfl_xor(part, 2, 64);                                 \
    part += __shfl_xor(part, 4, 64);                                 \
    float p = __expf(part * 0.17677669529663687f + EV);              \
    z += p;                                                          \
    a0 += p * __uint_as_float(KV.x & 0xFFFF0000u);                   \
    a1 += p * __uint_as_float(KV.y & 0xFFFF0000u);                   \
    a2 += p * __uint_as_float(KV.z & 0xFFFF0000u);                   \
    a3 += p * __uint_as_float(KV.w & 0xFFFF0000u); }

__global__ __launch_bounds__(256) void aggregate_kernel(
    const unsigned int* __restrict__ qkvr,  // [MROWS][512] uints (kv | qr pairs)
    const float* __restrict__ esum,         // [E][8] CSR order
    const int* __restrict__ offsets,
    const int* __restrict__ ssrc,           // [E] src in CSR order
    float* __restrict__ out) {              // [MROWS][256] fp32
  int t = threadIdx.x;
  int w = t >> 6, l = t & 63;
  int nb = blockIdx.x * 4 + w;              // grid 10000 -> 40000 waves
  int b = nb & 1, n = nb >> 1;
  int h = l >> 3;
  int beg = offsets[n], end = offsets[n + 1];

  uint4 qr4 = *(const uint4*)(qkvr + (size_t)nb * 512 + 256 + l * 4);
  float q0 = __uint_as_float(qr4.x << 16), q1 = __uint_as_float(qr4.y << 16);
  float q2 = __uint_as_float(qr4.z << 16), q3 = __uint_as_float(qr4.w << 16);

  const unsigned* kvl = qkvr + (size_t)b * 512 + l * 4;  // + s*1024 per edge

  float z = 0.f, a0 = 0.f, a1 = 0.f, a2 = 0.f, a3 = 0.f;

  for (int base = beg; base < end; base += 64) {
    int chunk = min(64, end - base);
    int s_l = (l < chunk) ? ssrc[base + l] : 0;
    const float* esp = esum + (size_t)base * 8 + h;
    uint4 k0 = {0,0,0,0}, k1 = {0,0,0,0}, k2 = {0,0,0,0};
    uint4 k3 = {0,0,0,0}, k4 = {0,0,0,0}, k5 = {0,0,0,0};
    float e0 = 0.f, e1 = 0.f, e2 = 0.f, e3 = 0.f, e4 = 0.f, e5 = 0.f;
    LOADSLOT(k0, e0, 0);
    if (chunk > 1) LOADSLOT(k1, e1, 1);
    if (chunk > 2) LOADSLOT(k2, e2, 2);
    if (chunk > 3) LOADSLOT(k3, e3, 3);
    if (chunk > 4) LOADSLOT(k4, e4, 4);
    if (chunk > 5) LOADSLOT(k5, e5, 5);
    for (int i = 0; i < chunk; i += 6) {
      CONSUME(k0, e0);
      if (i + 6 < chunk) LOADSLOT(k0, e0, i + 6);
      if (i + 1 < chunk) {
        CONSUME(k1, e1);
        if (i + 7 < chunk) LOADSLOT(k1, e1, i + 7);
        if (i + 2 < chunk) {
          CONSUME(k2, e2);
          if (i + 8 < chunk) LOADSLOT(k2, e2, i + 8);
          if (i + 3 < chunk) {
            CONSUME(k3, e3);
            if (i + 9 < chunk) LOADSLOT(k3, e3, i + 9);
            if (i + 4 < chunk) {
              CONSUME(k4, e4);
              if (i + 10 < chunk) LOADSLOT(k4, e4, i + 10);
              if (i + 5 < chunk) {
                CONSUME(k5, e5);
                if (i + 11 < chunk) LOADSLOT(k5, e5, i + 11);
              }
            }
          }
        }
      }
    }
  }
  float inv = (z > 0.f) ? (1.0f / z) : 0.f;
  float4 o = make_float4(a0 * inv + __uint_as_float(qr4.x & 0xFFFF0000u),
                         a1 * inv + __uint_as_float(qr4.y & 0xFFFF0000u),
                         a2 * inv + __uint_as_float(qr4.z & 0xFFFF0000u),
                         a3 * inv + __uint_as_float(qr4.w & 0xFFFF0000u));
  *(float4*)(out + (size_t)nb * 256 + l * 4) = o;
}

// ---------------------------------------------------------------------------
extern "C" void kernel_launch(void* const* d_in, const int* in_sizes, int n_in,
                              void* d_out, int out_size, void* d_ws, size_t ws_size,
                              hipStream_t stream) {
  (void)in_sizes; (void)n_in; (void)out_size; (void)ws_size;
  const float* x     = (const float*)d_in[0];
  const float* edata = (const float*)d_in[1];
  const int* esrc    = (const int*)d_in[2];
  const int* edst    = (const int*)d_in[3];
  const float* Wq    = (const float*)d_in[4];
  const float* bq    = (const float*)d_in[5];
  const float* Wk    = (const float*)d_in[6];
  const float* bk    = (const float*)d_in[7];
  const float* Wv    = (const float*)d_in[8];
  const float* bv    = (const float*)d_in[9];
  const float* We    = (const float*)d_in[10];
  const float* Wr    = (const float*)d_in[11];
  const float* br    = (const float*)d_in[12];
  float* out = (float*)d_out;     // fp32 output

  char* ws = (char*)d_ws;
  size_t off = 0;
  auto carve = [&](size_t bytes) -> void* {
    void* p = ws + off;
    off += (bytes + 255) & ~(size_t)255;
    return p;
  };
  int* counts    = (int*)carve((size_t)NN * 4);
  int* offsets   = (int*)carve((size_t)(NN + 1) * 4);
  int* cursor    = (int*)carve((size_t)NN * 4);
  int* ssrc      = (int*)carve((size_t)EE * 4);               // 1.28 MB
  __hip_bfloat16* wt = (__hip_bfloat16*)carve((size_t)1024 * 256 * 2);
  float* bcat    = (float*)carve(1024 * 4);
  float* wesum   = (float*)carve(8 * 64 * 4);
  float* esum    = (float*)carve((size_t)EE * 8 * 4);         // 10.24 MB
  __bf16* xb     = (__bf16*)carve((size_t)MROWS * 256 * 2);   // 20.5 MB
  __hip_bfloat16* qkvr = (__hip_bfloat16*)carve((size_t)MROWS * 1024 * 2); // 81.9 MB

  hipMemsetAsync(counts, 0, (size_t)NN * 4, stream);
  prep_kernel<<<17 + NB_HIST + NB_CVT, 256, 0, stream>>>(
      Wq, Wk, Wv, Wr, wt, bq, bk, bv, br, bcat, We, wesum, edst, counts, x, xb);
  scan_kernel<<<1, 256, 0, stream>>>(counts, offsets, cursor);
  scatter_esum<<<EE / 256, 256, 0, stream>>>(edst, esrc, cursor, edata, wesum,
                                             ssrc, esum);
  gemm_qkvr<<<dim3(4, 625), 256, 0, stream>>>(xb, (const __bf16*)wt, bcat, qkvr);
  aggregate_kernel<<<MROWS / 4, 256, 0, stream>>>((const unsigned int*)qkvr, esum,
                                                  offsets, ssrc, out);
}

// Round 5
// 382.146 us; speedup vs baseline: 1.3645x; 1.0908x over previous
//
#include <hip/hip_runtime.h>
#include <hip/hip_bf16.h>

#define NN    20000
#define BB    2
#define EE    320000
#define MROWS (NN * BB)   // 40000

typedef __bf16 bf16x8 __attribute__((ext_vector_type(8)));
typedef __bf16 bf16x4 __attribute__((ext_vector_type(4)));
typedef float  floatx4 __attribute__((ext_vector_type(4)));

// Channel permutation of the 1024 fused output channels (c = head*32+chan):
//   j in [0,512):    c = j>>1;        j even -> k[c], j odd -> v[c]
//   j in [512,1024): c = (j-512)>>1;  j even -> q[c], j odd -> r[c]
// So a uint32 at row*512 + c       = (k[c] | v[c]<<16)  (bf16 pair)
//    a uint32 at row*512 + 256 + c = (q[c] | r[c]<<16)

#define NB_HIST 1250   // (EE+255)/256
#define NB_CVT  1250   // MROWS*256 / 8192

// ---------------------------------------------------------------------------
// Merged prep: blocks 0..15 weight transpose+permute, 16 bias+wesum,
// 17..1266 dst histogram, 1267..2516 x -> bf16 convert.
// (counts zeroed by hipMemsetAsync beforehand.)
// ---------------------------------------------------------------------------
__global__ __launch_bounds__(256) void prep_kernel(
    const float* __restrict__ Wq, const float* __restrict__ Wk,
    const float* __restrict__ Wv, const float* __restrict__ Wr,
    __hip_bfloat16* __restrict__ wt,
    const float* __restrict__ bq, const float* __restrict__ bk,
    const float* __restrict__ bv, const float* __restrict__ br,
    float* __restrict__ bcat,
    const float* __restrict__ We, float* __restrict__ wesum,
    const int* __restrict__ edst, int* __restrict__ counts,
    const float* __restrict__ x, __bf16* __restrict__ xb) {
  __shared__ float TA[32][65];
  __shared__ float TB[32][65];
  int bt = blockIdx.x;
  int t = threadIdx.x;

  if (bt < 16) {
    const float *A, *B;
    int c0, jbase;
    if (bt < 8) { A = Wk; B = Wv; c0 = 32 * bt;      jbase = 64 * bt; }
    else        { A = Wq; B = Wr; c0 = 32 * (bt-8);  jbase = 512 + 64 * (bt-8); }
    int krow = t >> 2;                   // 0..63
    int cc = (t & 3) * 8;                // 0,8,16,24
    int sel = t >> 7;                    // write phase: 0->A, 1->B
    int u = t & 127;
    int ci = u >> 2;                     // 0..31
    int kk0 = (u & 3) * 16;              // 0,16,32,48

    for (int kt = 0; kt < 4; ++kt) {
      int k = kt * 64 + krow;
      float4 a0 = *(const float4*)(A + (size_t)k * 256 + c0 + cc);
      float4 a1 = *(const float4*)(A + (size_t)k * 256 + c0 + cc + 4);
      float4 b0 = *(const float4*)(B + (size_t)k * 256 + c0 + cc);
      float4 b1 = *(const float4*)(B + (size_t)k * 256 + c0 + cc + 4);
      __syncthreads();                   // previous write phase done
      TA[cc+0][krow]=a0.x; TA[cc+1][krow]=a0.y; TA[cc+2][krow]=a0.z; TA[cc+3][krow]=a0.w;
      TA[cc+4][krow]=a1.x; TA[cc+5][krow]=a1.y; TA[cc+6][krow]=a1.z; TA[cc+7][krow]=a1.w;
      TB[cc+0][krow]=b0.x; TB[cc+1][krow]=b0.y; TB[cc+2][krow]=b0.z; TB[cc+3][krow]=b0.w;
      TB[cc+4][krow]=b1.x; TB[cc+5][krow]=b1.y; TB[cc+6][krow]=b1.z; TB[cc+7][krow]=b1.w;
      __syncthreads();
      float (*T)[65] = sel ? TB : TA;
      int j = jbase + 2 * ci + sel;
      __hip_bfloat16* dst = wt + (size_t)j * 256 + kt * 64 + kk0;
      #pragma unroll
      for (int q = 0; q < 16; ++q) dst[q] = __float2bfloat16(T[ci][kk0 + q]);
    }
  } else if (bt == 16) {
    #pragma unroll
    for (int jj = 0; jj < 4; ++jj) {
      int j = jj * 256 + t;
      float val;
      if (j < 512) { int c = j >> 1;         val = (j & 1) ? bv[c] : bk[c]; }
      else         { int c = (j - 512) >> 1; val = (j & 1) ? br[c] : bq[c]; }
      bcat[j] = val;
    }
    #pragma unroll
    for (int ii = 0; ii < 2; ++ii) {
      int i = ii * 256 + t;
      int h = i >> 6, d = i & 63;
      float s = 0.f;
      for (int c = 0; c < 32; ++c) s += We[(size_t)d * 256 + h * 32 + c];
      wesum[h * 64 + d] = s;
    }
  } else if (bt < 17 + NB_HIST) {
    int e = (bt - 17) * 256 + t;
    if (e < EE) atomicAdd(&counts[edst[e]], 1);
  } else {
    int cb = bt - 17 - NB_HIST;          // 0..1249
    size_t base = (size_t)cb * 8192 + t * 4;
    #pragma unroll
    for (int j = 0; j < 8; ++j) {
      float4 v = *(const float4*)(x + base + j * 1024);
      bf16x4 o;
      o[0] = (__bf16)v.x; o[1] = (__bf16)v.y;
      o[2] = (__bf16)v.z; o[3] = (__bf16)v.w;
      *(bf16x4*)(xb + base + j * 1024) = o;
    }
  }
}

// ---------------------------------------------------------------------------
// 1-block scan of counts -> offsets, cursor. Counts staged through LDS so
// every global access is coalesced (the old per-thread 79-stride loop hit
// 256 distinct cache lines per instruction).
// ---------------------------------------------------------------------------
#define SCAN_PAD (79 * 256)   // 20224 >= NN
__global__ __launch_bounds__(256) void scan_kernel(
    const int* __restrict__ counts,
    int* __restrict__ offsets,
    int* __restrict__ cursor) {
  __shared__ int lc[SCAN_PAD];
  __shared__ int part[256];
  int t = threadIdx.x;
  for (int j = 0; j < 79; ++j) {
    int idx = j * 256 + t;
    lc[idx] = (idx < NN) ? counts[idx] : 0;
  }
  __syncthreads();
  int lo = t * 79;
  int s = 0;
  #pragma unroll 4
  for (int i = 0; i < 79; ++i) s += lc[lo + i];
  part[t] = s;
  __syncthreads();
  for (int off = 1; off < 256; off <<= 1) {
    int v = (t >= off) ? part[t - off] : 0;
    __syncthreads();
    part[t] += v;
    __syncthreads();
  }
  int base = (t == 0) ? 0 : part[t - 1];
  for (int i = 0; i < 79; ++i) {
    int c = lc[lo + i];
    lc[lo + i] = base;
    base += c;
  }
  if (t == 255) offsets[NN] = base;
  __syncthreads();
  for (int j = 0; j < 79; ++j) {
    int idx = j * 256 + t;
    if (idx < NN) {
      int v = lc[idx];
      offsets[idx] = v;
      cursor[idx]  = v;
    }
  }
}

// ---------------------------------------------------------------------------
// Fused scatter + edge-feature reduction: one pass over the edge list.
// Each edge grabs its CSR slot p, writes src there (coalesced read later in
// aggregate) and writes esum[p][h] = edata[e].wesum[h] directly pre-sorted.
// ---------------------------------------------------------------------------
__global__ __launch_bounds__(256) void scatter_esum(
    const int* __restrict__ edst, const int* __restrict__ esrc,
    int* __restrict__ cursor,
    const float* __restrict__ edata, const float* __restrict__ wesum,
    int* __restrict__ ssrc, float* __restrict__ esum) {
  __shared__ float wl[512];
  int t = threadIdx.x;
  wl[t] = wesum[t];
  wl[t + 256] = wesum[t + 256];
  __syncthreads();
  int e = blockIdx.x * 256 + t;        // EE = 1250*256 exactly
  int p = atomicAdd(&cursor[edst[e]], 1);
  ssrc[p] = esrc[e];
  float acc[8] = {};
  const float* row = edata + (size_t)e * 64;
  for (int d = 0; d < 64; d += 4) {
    float4 v = *(const float4*)(row + d);
    #pragma unroll
    for (int hh = 0; hh < 8; ++hh) {
      const float* wv = &wl[hh * 64 + d];
      acc[hh] += v.x * wv[0] + v.y * wv[1] + v.z * wv[2] + v.w * wv[3];
    }
  }
  float* op = esum + (size_t)p * 8;
  *(float4*)op       = make_float4(acc[0], acc[1], acc[2], acc[3]);
  *(float4*)(op + 4) = make_float4(acc[4], acc[5], acc[6], acc[7]);
}

// ---------------------------------------------------------------------------
// Fused q|k|v|r GEMM. B operand (wt, 0.5 MB, L2-resident) is read DIRECTLY
// from global into registers — no LDS staging for B at all. Each lane's
// fragment is a 16 B load; a wave's 64 lanes cover 16 full 64-B lines.
// All 8 B-fragments for the K-step are issued before the A barrier, so they
// are in flight across the A stage + ds_reads. LDS holds only the A tile
// (9.2 KB). BK=64, tile 64x256, 4 waves each 64x64 (4x4 frags), LSTR=72.
// ---------------------------------------------------------------------------
__global__ __launch_bounds__(256) void gemm_qkvr(
    const __bf16* __restrict__ xb,   // [MROWS][256] bf16
    const __bf16* __restrict__ wt,   // [1024][256] bf16 (n-major, permuted)
    const float* __restrict__ bcat,  // [1024] permuted
    __hip_bfloat16* __restrict__ out) {  // [MROWS][1024] bf16 permuted
  const int LSTR = 72;
  __shared__ __attribute__((aligned(16))) __bf16 As[64 * LSTR];

  int m0 = blockIdx.y * 64;
  int n0 = blockIdx.x * 256;
  int t = threadIdx.x;
  int w = t >> 6, l = t & 63;
  int lr = l & 15, lq = l >> 4;
  int ar = t >> 2, ac = (t & 3) * 16;   // A staging: row, col (16 elems/thr)

  floatx4 acc[4][4] = {};               // [mt][nt]
  const __bf16* wbase = wt + (size_t)(n0 + 64 * w + lr) * 256 + lq * 8;

  for (int ks = 0; ks < 4; ++ks) {
    const __bf16* xp = xb + (size_t)(m0 + ar) * 256 + ks * 64 + ac;
    bf16x8 a0 = *(const bf16x8*)xp;
    bf16x8 a1 = *(const bf16x8*)(xp + 8);
    bf16x8 bfr[2][4];
    #pragma unroll
    for (int kk = 0; kk < 2; ++kk)
      #pragma unroll
      for (int nt = 0; nt < 4; ++nt)
        bfr[kk][nt] = *(const bf16x8*)(wbase + (size_t)nt * 16 * 256 + ks * 64 + kk * 32);
    __syncthreads();                    // previous step's frag reads done
    *(bf16x8*)&As[ar * LSTR + ac]     = a0;
    *(bf16x8*)&As[ar * LSTR + ac + 8] = a1;
    __syncthreads();
    #pragma unroll
    for (int kk = 0; kk < 2; ++kk) {
      bf16x8 af[4];
      #pragma unroll
      for (int mt = 0; mt < 4; ++mt)
        af[mt] = *(const bf16x8*)&As[(16 * mt + lr) * LSTR + kk * 32 + lq * 8];
      #pragma unroll
      for (int mt = 0; mt < 4; ++mt)
        #pragma unroll
        for (int nt = 0; nt < 4; ++nt)
          acc[mt][nt] = __builtin_amdgcn_mfma_f32_16x16x32_bf16(af[mt], bfr[kk][nt], acc[mt][nt], 0, 0, 0);
    }
  }

  // C/D: col = lane&15, row = (lane>>4)*4 + reg
  #pragma unroll
  for (int mt = 0; mt < 4; ++mt)
    #pragma unroll
    for (int nt = 0; nt < 4; ++nt)
      #pragma unroll
      for (int r = 0; r < 4; ++r) {
        int gr = m0 + 16 * mt + lq * 4 + r;
        int gc = n0 + 64 * w + 16 * nt + lr;
        out[(size_t)gr * 1024 + gc] = __float2bfloat16(acc[mt][nt][r] + bcat[gc]);
      }
}

// ---------------------------------------------------------------------------
// Fused logits + softmax + V-aggregation + residual, fp32 out.
// ONE WAVE per (dst,b) — 40000 waves for max TLP; lane l owns channels
// 4l..4l+3 (head h = l>>3). Depth-6 software pipeline, no register rotation:
// 6 dwordx4 kv-gathers + 6 esum loads in flight per wave; all guards
// wave-uniform. No online-max (logits bounded, exp() direct).
// ---------------------------------------------------------------------------
#define LOADSLOT(KV, EV, IDX)                                        \
  { int s_ = __builtin_amdgcn_readlane(s_l, (IDX));                  \
    KV = *(const uint4*)(kvl + (size_t)s_ * 1024);                   \
    EV = esp[(size_t)(IDX) * 8]; }

#define CONSUME(KV, EV)                                              \
  { float part = __uint_as_float(KV.x << 16) * q0                    \
               + __uint_as_float(KV.y << 16) * q1                    \
               + __uint_as_float(KV.z << 16) * q2                    \
               + __uint_as_float(KV.w << 16) * q3;                   \
    part += __shfl_xor(part, 1, 64);                                 \
    part += __shfl_xor(part, 2, 64);                                 \
    part += __shfl_xor(part, 4, 64);                                 \
    float p = __expf(part * 0.17677669529663687f + EV);              \
    z += p;                                                          \
    a0 += p * __uint_as_float(KV.x & 0xFFFF0000u);                   \
    a1 += p * __uint_as_float(KV.y & 0xFFFF0000u);                   \
    a2 += p * __uint_as_float(KV.z & 0xFFFF0000u);                   \
    a3 += p * __uint_as_float(KV.w & 0xFFFF0000u); }

__global__ __launch_bounds__(256) void aggregate_kernel(
    const unsigned int* __restrict__ qkvr,  // [MROWS][512] uints (kv | qr pairs)
    const float* __restrict__ esum,         // [E][8] CSR order
    const int* __restrict__ offsets,
    const int* __restrict__ ssrc,           // [E] src in CSR order
    float* __restrict__ out) {              // [MROWS][256] fp32
  int t = threadIdx.x;
  int w = t >> 6, l = t & 63;
  int nb = blockIdx.x * 4 + w;              // grid 10000 -> 40000 waves
  int b = nb & 1, n = nb >> 1;
  int h = l >> 3;
  int beg = offsets[n], end = offsets[n + 1];

  uint4 qr4 = *(const uint4*)(qkvr + (size_t)nb * 512 + 256 + l * 4);
  float q0 = __uint_as_float(qr4.x << 16), q1 = __uint_as_float(qr4.y << 16);
  float q2 = __uint_as_float(qr4.z << 16), q3 = __uint_as_float(qr4.w << 16);

  const unsigned* kvl = qkvr + (size_t)b * 512 + l * 4;  // + s*1024 per edge

  float z = 0.f, a0 = 0.f, a1 = 0.f, a2 = 0.f, a3 = 0.f;

  for (int base = beg; base < end; base += 64) {
    int chunk = min(64, end - base);
    int s_l = (l < chunk) ? ssrc[base + l] : 0;
    const float* esp = esum + (size_t)base * 8 + h;
    uint4 k0 = {0,0,0,0}, k1 = {0,0,0,0}, k2 = {0,0,0,0};
    uint4 k3 = {0,0,0,0}, k4 = {0,0,0,0}, k5 = {0,0,0,0};
    float e0 = 0.f, e1 = 0.f, e2 = 0.f, e3 = 0.f, e4 = 0.f, e5 = 0.f;
    LOADSLOT(k0, e0, 0);
    if (chunk > 1) LOADSLOT(k1, e1, 1);
    if (chunk > 2) LOADSLOT(k2, e2, 2);
    if (chunk > 3) LOADSLOT(k3, e3, 3);
    if (chunk > 4) LOADSLOT(k4, e4, 4);
    if (chunk > 5) LOADSLOT(k5, e5, 5);
    for (int i = 0; i < chunk; i += 6) {
      CONSUME(k0, e0);
      if (i + 6 < chunk) LOADSLOT(k0, e0, i + 6);
      if (i + 1 < chunk) {
        CONSUME(k1, e1);
        if (i + 7 < chunk) LOADSLOT(k1, e1, i + 7);
        if (i + 2 < chunk) {
          CONSUME(k2, e2);
          if (i + 8 < chunk) LOADSLOT(k2, e2, i + 8);
          if (i + 3 < chunk) {
            CONSUME(k3, e3);
            if (i + 9 < chunk) LOADSLOT(k3, e3, i + 9);
            if (i + 4 < chunk) {
              CONSUME(k4, e4);
              if (i + 10 < chunk) LOADSLOT(k4, e4, i + 10);
              if (i + 5 < chunk) {
                CONSUME(k5, e5);
                if (i + 11 < chunk) LOADSLOT(k5, e5, i + 11);
              }
            }
          }
        }
      }
    }
  }
  float inv = (z > 0.f) ? (1.0f / z) : 0.f;
  float4 o = make_float4(a0 * inv + __uint_as_float(qr4.x & 0xFFFF0000u),
                         a1 * inv + __uint_as_float(qr4.y & 0xFFFF0000u),
                         a2 * inv + __uint_as_float(qr4.z & 0xFFFF0000u),
                         a3 * inv + __uint_as_float(qr4.w & 0xFFFF0000u));
  *(float4*)(out + (size_t)nb * 256 + l * 4) = o;
}

// ---------------------------------------------------------------------------
extern "C" void kernel_launch(void* const* d_in, const int* in_sizes, int n_in,
                              void* d_out, int out_size, void* d_ws, size_t ws_size,
                              hipStream_t stream) {
  (void)in_sizes; (void)n_in; (void)out_size; (void)ws_size;
  const float* x     = (const float*)d_in[0];
  const float* edata = (const float*)d_in[1];
  const int* esrc    = (const int*)d_in[2];
  const int* edst    = (const int*)d_in[3];
  const float* Wq    = (const float*)d_in[4];
  const float* bq    = (const float*)d_in[5];
  const float* Wk    = (const float*)d_in[6];
  const float* bk    = (const float*)d_in[7];
  const float* Wv    = (const float*)d_in[8];
  const float* bv    = (const float*)d_in[9];
  const float* We    = (const float*)d_in[10];
  const float* Wr    = (const float*)d_in[11];
  const float* br    = (const float*)d_in[12];
  float* out = (float*)d_out;     // fp32 output

  char* ws = (char*)d_ws;
  size_t off = 0;
  auto carve = [&](size_t bytes) -> void* {
    void* p = ws + off;
    off += (bytes + 255) & ~(size_t)255;
    return p;
  };
  int* counts    = (int*)carve((size_t)NN * 4);
  int* offsets   = (int*)carve((size_t)(NN + 1) * 4);
  int* cursor    = (int*)carve((size_t)NN * 4);
  int* ssrc      = (int*)carve((size_t)EE * 4);               // 1.28 MB
  __hip_bfloat16* wt = (__hip_bfloat16*)carve((size_t)1024 * 256 * 2);
  float* bcat    = (float*)carve(1024 * 4);
  float* wesum   = (float*)carve(8 * 64 * 4);
  float* esum    = (float*)carve((size_t)EE * 8 * 4);         // 10.24 MB
  __bf16* xb     = (__bf16*)carve((size_t)MROWS * 256 * 2);   // 20.5 MB
  __hip_bfloat16* qkvr = (__hip_bfloat16*)carve((size_t)MROWS * 1024 * 2); // 81.9 MB

  hipMemsetAsync(counts, 0, (size_t)NN * 4, stream);
  prep_kernel<<<17 + NB_HIST + NB_CVT, 256, 0, stream>>>(
      Wq, Wk, Wv, Wr, wt, bq, bk, bv, br, bcat, We, wesum, edst, counts, x, xb);
  scan_kernel<<<1, 256, 0, stream>>>(counts, offsets, cursor);
  scatter_esum<<<EE / 256, 256, 0, stream>>>(edst, esrc, cursor, edata, wesum,
                                             ssrc, esum);
  gemm_qkvr<<<dim3(4, 625), 256, 0, stream>>>(xb, (const __bf16*)wt, bcat, qkvr);
  aggregate_kernel<<<MROWS / 4, 256, 0, stream>>>((const unsigned int*)qkvr, esum,
                                                  offsets, ssrc, out);
}